// Round 12
// baseline (622.433 us; speedup 1.0000x reference)
//
#include <hip/hip_runtime.h>

typedef __attribute__((ext_vector_type(8))) short short8;
typedef __attribute__((ext_vector_type(4))) float f32x4;
typedef unsigned short u16;
typedef unsigned int u32;
typedef unsigned long long u64;

// params layout (floats)
#define P_WH 0
#define P_WI 2
#define P_WA 4
#define P_WW 6
#define SL_AX 8
#define SL_WUP 12
#define SL_WGATE 16
#define SL_WDOWN 20
#define SL_AH 24
#define P_SX 28
#define P_SWUP 32
#define P_SWGATE 40
#define P_SWDOWN 48
#define P_SH 56

__device__ __forceinline__ u16 f2bf(float f) {
  u32 u = __float_as_uint(f);
  u = (u + 0x7FFFu + ((u >> 16) & 1u)) >> 16;
  return (u16)u;
}
__device__ __forceinline__ float bf2f(u16 h) { return __uint_as_float(((u32)h) << 16); }
__device__ __forceinline__ float fquant(float v, float s) { return rintf(v / s) * s; }

typedef const __attribute__((address_space(1))) u32 gl_u32;
typedef __attribute__((address_space(3))) u32 lds_u32;
__device__ __forceinline__ void gload_lds16(const void* g, void* l) {
  __builtin_amdgcn_global_load_lds((gl_u32*)g, (lds_u32*)l, 16, 0, 0);
}

#define WAITVM8()  asm volatile("s_waitcnt vmcnt(8)" ::: "memory")
#define WAITVM2()  asm volatile("s_waitcnt vmcnt(2)" ::: "memory")
#define WAITVM0()  asm volatile("s_waitcnt vmcnt(0)" ::: "memory")
#define BARRIER()  asm volatile("s_barrier" ::: "memory")

// ---- init: zero absmax slots, compute the four 2-way softmaxes ----
__global__ void k_init(const float* ph, const float* pi, const float* pa,
                       const float* pw, float* P) {
  if (threadIdx.x == 0) {
    u32* U = (u32*)P;
    for (int i = SL_AX; i < SL_AH + 2; ++i) U[i] = 0u;
    const float* src[4] = {ph, pi, pa, pw};
    #pragma unroll
    for (int t = 0; t < 4; ++t) {
      float a = src[t][0], b = src[t][1];
      float mx = fmaxf(a, b);
      float ea = expf(a - mx), eb = expf(b - mx);
      float s = ea + eb;
      P[t * 2 + 0] = ea / s;
      P[t * 2 + 1] = eb / s;
    }
  }
}

// ---- quadrant absmax: branchless, ILP-4, pow2 fast path, block-reduced ----
template <bool POW2>
__device__ __forceinline__ void amax_proc(float4 d, int v, u32 magic, int C,
                                          int r0, int c0,
                                          float& m0, float& m1, float& m2, float& m3) {
  int lin = v << 2;
  int o, c;
  if (POW2) { o = lin >> 11; c = lin & 2047; }
  else {
    o = (int)(((u64)(u32)lin * magic) >> 40);
    c = lin - o * C;
  }
  float mm = fmaxf(fmaxf(fabsf(d.x), fabsf(d.y)), fmaxf(fabsf(d.z), fabsf(d.w)));
  bool rlo = o < r0, clo = c < c0;
  m0 = fmaxf(m0, (rlo && clo) ? mm : 0.f);
  m1 = fmaxf(m1, (rlo && !clo) ? mm : 0.f);
  m2 = fmaxf(m2, (!rlo && clo) ? mm : 0.f);
  m3 = fmaxf(m3, (!rlo && !clo) ? mm : 0.f);
}

template <bool POW2>
__device__ __forceinline__ void absmax_dev(const float4* __restrict__ A4,
                                           int nvec, u32 magic, int C, int r0, int c0,
                                           int slotbase, float* P, int bid, int nb) {
  float m0 = 0.f, m1 = 0.f, m2 = 0.f, m3 = 0.f;
  const int tid = threadIdx.x;
  const int step = nb * 256;
  int v = bid * 256 + tid;
  for (; v + 3 * step < nvec; v += 4 * step) {
    float4 d0 = A4[v];
    float4 d1 = A4[v + step];
    float4 d2 = A4[v + 2 * step];
    float4 d3 = A4[v + 3 * step];
    amax_proc<POW2>(d0, v,            magic, C, r0, c0, m0, m1, m2, m3);
    amax_proc<POW2>(d1, v + step,     magic, C, r0, c0, m0, m1, m2, m3);
    amax_proc<POW2>(d2, v + 2 * step, magic, C, r0, c0, m0, m1, m2, m3);
    amax_proc<POW2>(d3, v + 3 * step, magic, C, r0, c0, m0, m1, m2, m3);
  }
  for (; v < nvec; v += step) {
    float4 d0 = A4[v];
    amax_proc<POW2>(d0, v, magic, C, r0, c0, m0, m1, m2, m3);
  }
  #pragma unroll
  for (int off = 32; off > 0; off >>= 1) {
    m0 = fmaxf(m0, __shfl_xor(m0, off));
    m1 = fmaxf(m1, __shfl_xor(m1, off));
    m2 = fmaxf(m2, __shfl_xor(m2, off));
    m3 = fmaxf(m3, __shfl_xor(m3, off));
  }
  __shared__ float red[16];
  const int wave = tid >> 6;
  if ((tid & 63) == 0) {
    red[wave * 4 + 0] = m0;
    red[wave * 4 + 1] = m1;
    red[wave * 4 + 2] = m2;
    red[wave * 4 + 3] = m3;
  }
  __syncthreads();
  if (tid < 4) {
    float mm = fmaxf(fmaxf(red[tid], red[4 + tid]), fmaxf(red[8 + tid], red[12 + tid]));
    if (mm > 0.f) atomicMax((u32*)P + slotbase + tid, __float_as_uint(mm));
  }
}

__global__ __launch_bounds__(256) void k_absmax4(const float* x, const float* Wu,
                                                 const float* Wg, const float* Wd,
                                                 u32 magic5504, float* P) {
  int b = blockIdx.x;
  if (b < 256)        absmax_dev<true >((const float4*)x,  (1024 * 2048) >> 2, 0, 2048, 1024, 1024, SL_AX,    P, b,        256);
  else if (b < 768)   absmax_dev<true >((const float4*)Wu, (5504 * 2048) >> 2, 0, 2048, 2752, 1024, SL_WUP,   P, b - 256,  512);
  else if (b < 1280)  absmax_dev<true >((const float4*)Wg, (5504 * 2048) >> 2, 0, 2048, 2752, 1024, SL_WGATE, P, b - 768,  512);
  else                absmax_dev<false>((const float4*)Wd, (2048 * 5504) >> 2, magic5504, 5504, 1024, 2752, SL_WDOWN, P, b - 1280, 512);
}

// ---- scales ----
__global__ void k_params1(float* P) {
  if (threadIdx.x != 0 || blockIdx.x != 0) return;
  u32* U = (u32*)P;
  float x00 = __uint_as_float(U[SL_AX + 0]);
  float x01 = __uint_as_float(U[SL_AX + 1]);
  float ax0 = x00;
  float ax1 = fmaxf(x00, x01);
  P[P_SX + 0] = fmaxf(ax0 / 7.f, 1e-8f);
  P[P_SX + 1] = fmaxf(ax0 / 127.f, 1e-8f);
  P[P_SX + 2] = fmaxf(ax1 / 7.f, 1e-8f);
  P[P_SX + 3] = fmaxf(ax1 / 127.f, 1e-8f);
  const int sl[3] = {SL_WUP, SL_WGATE, SL_WDOWN};
  const int sb[3] = {P_SWUP, P_SWGATE, P_SWDOWN};
  #pragma unroll
  for (int t = 0; t < 3; ++t) {
    float q00 = __uint_as_float(U[sl[t] + 0]);
    float q01 = __uint_as_float(U[sl[t] + 1]);
    float q10 = __uint_as_float(U[sl[t] + 2]);
    float q11 = __uint_as_float(U[sl[t] + 3]);
    float a0 = q00;
    float a1 = fmaxf(q00, q10);
    float a2 = fmaxf(q00, q01);
    float a3 = fmaxf(fmaxf(q00, q01), fmaxf(q10, q11));
    float aa[4] = {a0, a1, a2, a3};
    #pragma unroll
    for (int ij = 0; ij < 4; ++ij) {
      P[sb[t] + ij * 2 + 0] = fmaxf(aa[ij] / 7.f, 1e-8f);
      P[sb[t] + ij * 2 + 1] = fmaxf(aa[ij] / 127.f, 1e-8f);
    }
  }
}

__global__ void k_params2(float* P) {
  if (threadIdx.x != 0 || blockIdx.x != 0) return;
  u32* U = (u32*)P;
  float a0 = __uint_as_float(U[SL_AH]);
  float a1 = fmaxf(a0, __uint_as_float(U[SL_AH + 1]));
  P[P_SH + 0] = fmaxf(a0 / 7.f, 1e-8f);
  P[P_SH + 1] = fmaxf(a0 / 127.f, 1e-8f);
  P[P_SH + 2] = fmaxf(a1 / 7.f, 1e-8f);
  P[P_SH + 3] = fmaxf(a1 / 127.f, 1e-8f);
}

// ---- build activation operand element (chunk-XOR pre-swizzled) ----
__device__ __forceinline__ void build_x_one(
    const float* __restrict__ src, const float* __restrict__ P,
    u16* __restrict__ Xh, u16* __restrict__ Xl,
    int Csrc, int cin0, int K, int sbx, int gid, int kpr) {
  int row = gid / kpr;
  int kc_out = (gid - row * kpr) << 3;
  int kc_log = kc_out ^ (((row >> 1) & 3) << 3);
  int i = (kc_log >= cin0) ? 1 : 0;
  int c = kc_log - i * cin0;
  float pin = P[P_WH + i];
  float wa0 = P[P_WA], wa1 = P[P_WA + 1];
  float s4 = P[sbx + i * 2], s8 = P[sbx + i * 2 + 1];
  const float* sp = src + (size_t)row * Csrc + c;
  float v[8];
  *(float4*)&v[0] = *(const float4*)sp;
  *(float4*)&v[4] = *(const float4*)(sp + 4);
  short8 hv, lv;
  #pragma unroll
  for (int e = 0; e < 8; ++e) {
    float val = pin * (wa0 * fquant(v[e], s4) + wa1 * fquant(v[e], s8));
    u16 h = f2bf(val);
    hv[e] = (short)h;
    lv[e] = (short)f2bf(val - bf2f(h));
  }
  size_t off = (size_t)row * K + kc_out;
  *(short8*)(Xh + off) = hv;
  *(short8*)(Xl + off) = lv;
}

// ---- build weight operand element (chunk-XOR pre-swizzled) ----
__device__ __forceinline__ void build_w_one(
    const float* __restrict__ W, const float* __restrict__ P,
    u16* __restrict__ Wh, u16* __restrict__ Wl,
    int Csrc, int cin0, int K, int sbw, int cout0, int rowoff,
    int gid, int kpr) {
  int row = gid / kpr;
  int kc_out = (gid - row * kpr) << 3;
  int kc_log = kc_out ^ (((row >> 1) & 3) << 3);
  int i = (kc_log >= cin0) ? 1 : 0;
  int c = kc_log - i * cin0;
  float wi0 = P[P_WI], wi1 = P[P_WI + 1];
  float ww0 = P[P_WW], ww1 = P[P_WW + 1];
  float s00 = P[sbw + i * 4 + 0];
  float s01 = P[sbw + i * 4 + 1];
  float s10 = P[sbw + i * 4 + 2];
  float s11 = P[sbw + i * 4 + 3];
  float keep0 = (row < cout0) ? wi0 : 0.f;
  const float* sp = W + (size_t)row * Csrc + c;
  float v[8];
  *(float4*)&v[0] = *(const float4*)sp;
  *(float4*)&v[4] = *(const float4*)(sp + 4);
  short8 hv, lv;
  #pragma unroll
  for (int e = 0; e < 8; ++e) {
    float w = v[e];
    float t0 = ww0 * fquant(w, s00) + ww1 * fquant(w, s01);
    float t1 = ww0 * fquant(w, s10) + ww1 * fquant(w, s11);
    float val = keep0 * t0 + wi1 * t1;
    u16 h = f2bf(val);
    hv[e] = (short)h;
    lv[e] = (short)f2bf(val - bf2f(h));
  }
  size_t off = (size_t)(row + rowoff) * K + kc_out;
  *(short8*)(Wh + off) = hv;
  *(short8*)(Wl + off) = lv;
}

// standalone builders (fallback path)
__global__ __launch_bounds__(256) void k_build_x(
    const float* __restrict__ src, const float* __restrict__ P,
    u16* __restrict__ Xh, u16* __restrict__ Xl,
    int rows, int Csrc, int cin0, int K, int sbx) {
  int kpr = K >> 3;
  int nch = rows * kpr;
  int gid = blockIdx.x * blockDim.x + threadIdx.x;
  if (gid >= nch) return;
  build_x_one(src, P, Xh, Xl, Csrc, cin0, K, sbx, gid, kpr);
}

__global__ __launch_bounds__(256) void k_build_w(
    const float* __restrict__ W, const float* __restrict__ P,
    u16* __restrict__ Wh, u16* __restrict__ Wl,
    int R, int Csrc, int cin0, int K, int sbw, int cout0) {
  int kpr = K >> 3;
  int nch = R * kpr;
  int gid = blockIdx.x * blockDim.x + threadIdx.x;
  if (gid >= nch) return;
  build_w_one(W, P, Wh, Wl, Csrc, cin0, K, sbw, cout0, 0, gid, kpr);
}

// merged phase-1 build: x (1536 blocks) + Wu/Wg (16512 blocks)
__global__ __launch_bounds__(256) void k_build1(
    const float* __restrict__ x, const float* __restrict__ Wu,
    const float* __restrict__ Wg, const float* __restrict__ P,
    u16* __restrict__ X1h, u16* __restrict__ X1l,
    u16* __restrict__ Wh, u16* __restrict__ Wl) {
  int bid = blockIdx.x;
  if (bid < 1536) {
    int gid = bid * 256 + threadIdx.x;
    build_x_one(x, P, X1h, X1l, 2048, 1024, 3072, P_SX, gid, 384);
  } else {
    int gid = (bid - 1536) * 256 + threadIdx.x;
    const int nch = 5504 * 384;
    if (gid < nch)
      build_w_one(Wu, P, Wh, Wl, 2048, 1024, 3072, P_SWUP,   2752, 0,    gid,       384);
    else
      build_w_one(Wg, P, Wh, Wl, 2048, 1024, 3072, P_SWGATE, 2752, 5504, gid - nch, 384);
  }
}

// merged phase-2 build: x2 (4128 blocks) + Wd (8256 blocks)
__global__ __launch_bounds__(256) void k_build2(
    const float* __restrict__ H, const float* __restrict__ Wd,
    const float* __restrict__ P,
    u16* __restrict__ X2h, u16* __restrict__ X2l,
    u16* __restrict__ Wdh, u16* __restrict__ Wdl) {
  int bid = blockIdx.x;
  if (bid < 4128) {
    int gid = bid * 256 + threadIdx.x;
    build_x_one(H, P, X2h, X2l, 5504, 2752, 8256, P_SH, gid, 1032);
  } else {
    int gid = (bid - 4128) * 256 + threadIdx.x;
    build_w_one(Wd, P, Wdh, Wdl, 5504, 2752, 8256, P_SWDOWN, 1024, 0, gid, 1032);
  }
}

// ---- h = silu(gate)*up, fused h-absmax. H aliases UP (same-index). ----
__global__ __launch_bounds__(256) void k_h(const float* __restrict__ U_,
                                           const float* __restrict__ G_,
                                           float* __restrict__ H_, float* P) {
  int nvec = (1024 * 5504) >> 2;
  int gstride = gridDim.x * blockDim.x;
  float m0 = 0.f, m1 = 0.f;
  for (int v = blockIdx.x * blockDim.x + threadIdx.x; v < nvec; v += gstride) {
    float4 u = ((const float4*)U_)[v];
    float4 g = ((const float4*)G_)[v];
    float4 h;
    h.x = u.x * (g.x / (1.f + expf(-g.x)));
    h.y = u.y * (g.y / (1.f + expf(-g.y)));
    h.z = u.z * (g.z / (1.f + expf(-g.z)));
    h.w = u.w * (g.w / (1.f + expf(-g.w)));
    ((float4*)H_)[v] = h;
    int c = (v << 2) % 5504;
    float mm = fmaxf(fmaxf(fabsf(h.x), fabsf(h.y)), fmaxf(fabsf(h.z), fabsf(h.w)));
    if (c < 2752) m0 = fmaxf(m0, mm); else m1 = fmaxf(m1, mm);
  }
  #pragma unroll
  for (int off = 32; off > 0; off >>= 1) {
    m0 = fmaxf(m0, __shfl_xor(m0, off));
    m1 = fmaxf(m1, __shfl_xor(m1, off));
  }
  if ((threadIdx.x & 63) == 0) {
    u32* slots = (u32*)P;
    if (m0 > 0.f) atomicMax(slots + SL_AH, __float_as_uint(m0));
    if (m1 > 0.f) atomicMax(slots + SL_AH + 1, __float_as_uint(m1));
  }
}

// ---- bf16x3 MFMA GEMM (proven 2-phase 128x128) — fallback path only ----
template <int MF, int NF>
__global__ __launch_bounds__(256) void k_gemm(
    const u16* __restrict__ Ah, const u16* __restrict__ Al,
    const u16* __restrict__ Bh, const u16* __restrict__ Bl,
    float* __restrict__ C0, float* __restrict__ C1, int nsplit, int ldc,
    int M, int N, int K) {
  constexpr int BM = MF * 32;
  constexpr int BN = NF * 32;
  constexpr int HALF = (2 * BM + 2 * BN) * 32;
  constexpr int nsegA = BM / 16;
  constexpr int nsegB = BN / 16;
  constexpr int NSEG = 2 * nsegA + 2 * nsegB;
  constexpr int NJ = NSEG / 4;
  static_assert(NJ == 8, "vmcnt immediates assume 8 loads per stage");
  __shared__ __align__(16) u16 S[2 * HALF];

  const int tid = threadIdx.x;
  const int wave = tid >> 6;
  const int lane = tid & 63;

  const int gx = gridDim.x;
  const int nwg = gx * gridDim.y;
  const int orig = blockIdx.y * gx + blockIdx.x;
  const int q = nwg >> 3, r = nwg & 7;
  const int xcd = orig & 7, linb = orig >> 3;
  const int swz = (xcd < r ? xcd * (q + 1) : r * (q + 1) + (xcd - r) * q) + linb;
  const int m0 = (swz % gx) * BM;
  const int n0 = (swz / gx) * BN;

  const int St = K >> 5;
  const int Z = gridDim.z;
  const int zb = St / Z, zr = St - zb * Z;
  const int z = blockIdx.z;
  const int nst = zb + ((z < zr) ? 1 : 0);
  const int k0 = (z * zb + ((z < zr) ? z : zr)) << 5;

  const int wr = wave >> 1, wc = wave & 1;
  const int lrow = lane >> 2;
  const int lcol = (lane & 3) << 3;
  const int fr = lane & 15;
  const int fq4 = (lane >> 4) << 2;
  const int kofs = (lane >> 4) << 3;

  f32x4 acc[MF][NF];
  #pragma unroll
  for (int m = 0; m < MF; ++m)
    #pragma unroll
    for (int n = 0; n < NF; ++n) acc[m][n] = (f32x4){0.f, 0.f, 0.f, 0.f};

  const u16* srcp[NJ];
  int loff[NJ];
  #pragma unroll
  for (int j = 0; j < NJ; ++j) {
    int g = j * 4 + wave;
    const u16* gb; int abase, trow, segi;
    if (g < nsegA)               { gb = Ah; abase = 0;                  trow = m0; segi = g; }
    else if (g < 2 * nsegA)      { gb = Al; abase = BM * 32;            trow = m0; segi = g - nsegA; }
    else if (g < 2 * nsegA + nsegB) { gb = Bh; abase = 2 * BM * 32;     trow = n0; segi = g - 2 * nsegA; }
    else                         { gb = Bl; abase = 2 * BM * 32 + BN * 32; trow = n0; segi = g - 2 * nsegA - nsegB; }
    srcp[j] = gb + (size_t)(trow + segi * 16 + lrow) * K + (k0 + lcol);
    loff[j] = abase + segi * 512;
  }

  int aoh[MF], aol[MF], boh[NF], bol[NF];
  #pragma unroll
  for (int m = 0; m < MF; ++m) {
    int rr = wr * (MF * 16) + m * 16 + fr;
    int idx = rr * 32 + (kofs ^ (((rr >> 1) & 3) << 3));
    aoh[m] = idx;
    aol[m] = BM * 32 + idx;
  }
  #pragma unroll
  for (int n = 0; n < NF; ++n) {
    int rr = wc * (NF * 16) + n * 16 + fr;
    int idx = rr * 32 + (kofs ^ (((rr >> 1) & 3) << 3));
    boh[n] = 2 * BM * 32 + idx;
    bol[n] = 2 * BM * 32 + BN * 32 + idx;
  }

  #define STAGE(bufo)                                           \
    { _Pragma("unroll")                                         \
      for (int j = 0; j < NJ; ++j) {                            \
        gload_lds16(srcp[j], S + (bufo) + loff[j]);             \
        srcp[j] += 32;                                          \
      } }

  #define COMPUTE(bufo)                                                         \
    { short8 afh[MF], afl[MF], bfh[NF], bfl[NF];                                \
      _Pragma("unroll")                                                         \
      for (int m = 0; m < MF; ++m) {                                            \
        afh[m] = *(const short8*)(S + (bufo) + aoh[m]);                         \
        afl[m] = *(const short8*)(S + (bufo) + aol[m]);                         \
      }                                                                         \
      _Pragma("unroll")                                                         \
      for (int n = 0; n < NF; ++n) {                                            \
        bfh[n] = *(const short8*)(S + (bufo) + boh[n]);                         \
        bfl[n] = *(const short8*)(S + (bufo) + bol[n]);                         \
      }                                                                         \
      _Pragma("unroll")                                                         \
      for (int m = 0; m < MF; ++m)                                              \
        _Pragma("unroll")                                                       \
        for (int n = 0; n < NF; ++n) {                                          \
          acc[m][n] = __builtin_amdgcn_mfma_f32_16x16x32_bf16(afh[m], bfh[n], acc[m][n], 0, 0, 0); \
          acc[m][n] = __builtin_amdgcn_mfma_f32_16x16x32_bf16(afh[m], bfl[n], acc[m][n], 0, 0, 0); \
          acc[m][n] = __builtin_amdgcn_mfma_f32_16x16x32_bf16(afl[m], bfh[n], acc[m][n], 0, 0, 0); \
        } }

  int curo = 0;
  STAGE(curo);
  for (int t = 0; t + 1 < nst; ++t) {
    STAGE(curo ^ HALF);
    WAITVM8();
    BARRIER();
    COMPUTE(curo);
    BARRIER();
    curo ^= HALF;
  }
  WAITVM0();
  BARRIER();
  COMPUTE(curo);

  #undef STAGE
  #undef COMPUTE

  float* base = (n0 < nsplit) ? C0 : C1;
  const int ncol0 = (n0 < nsplit) ? 0 : nsplit;
  float* Cz = base + (size_t)z * M * ldc;
  #pragma unroll
  for (int m = 0; m < MF; ++m) {
    #pragma unroll
    for (int n = 0; n < NF; ++n) {
      int row = m0 + wr * (MF * 16) + m * 16 + fq4;
      int col = n0 + wc * (NF * 16) + n * 16 + fr - ncol0;
      float* cp = Cz + (size_t)row * ldc + col;
      f32x4 a = acc[m][n];
      cp[0] = a[0];
      cp[(size_t)ldc] = a[1];
      cp[(size_t)2 * ldc] = a[2];
      cp[(size_t)3 * ldc] = a[3];
    }
  }
}

// ---- 8-phase bf16x3 GEMM (T3+T4+T5, proven r11): BM=256, BN=128, BK=32,
//      8 waves (2x4, wave=128x32 out), 96KB LDS (1 blk/CU). Split C-write
//      epilogue (n0 < nsplit -> C0 else C1 at col-nsplit, row stride ldc). ----
__global__ __launch_bounds__(512) void k_gemm8(
    const u16* __restrict__ Ah, const u16* __restrict__ Al,
    const u16* __restrict__ Bh, const u16* __restrict__ Bl,
    float* __restrict__ C0, float* __restrict__ C1, int nsplit, int ldc,
    int M, int N, int K) {
  constexpr int BM = 256, BN = 128;
  constexpr int HALF = (2 * BM + 2 * BN) * 32;   // 24576 u16 = 48 KB
  constexpr int NJ = 6;
  __shared__ __align__(16) u16 S[2 * HALF];      // 96 KB

  const int tid = threadIdx.x;
  const int wave = tid >> 6;   // 0..7
  const int lane = tid & 63;

  const int gx = gridDim.x;
  const int nwg = gx * gridDim.y;
  const int orig = blockIdx.y * gx + blockIdx.x;
  const int q = nwg >> 3, r = nwg & 7;
  const int xcd = orig & 7, linb = orig >> 3;
  const int swz = (xcd < r ? xcd * (q + 1) : r * (q + 1) + (xcd - r) * q) + linb;
  const int m0 = (swz % gx) * BM;
  const int n0 = (swz / gx) * BN;

  const int St = K >> 5;
  const int Z = gridDim.z;
  const int zb = St / Z, zr = St - zb * Z;
  const int z = blockIdx.z;
  const int nst = zb + ((z < zr) ? 1 : 0);
  const int k0 = (z * zb + ((z < zr) ? z : zr)) << 5;

  const int wr = wave >> 2;    // 0..1  (rows)
  const int wc = wave & 3;     // 0..3  (cols)
  const int lrow = lane >> 2;
  const int lcol = (lane & 3) << 3;
  const int fr = lane & 15;
  const int fq4 = (lane >> 4) << 2;
  const int kofs = (lane >> 4) << 3;
  const int kx = kofs ^ (((fr >> 1) & 3) << 3);

  f32x4 acc[8][2];
  #pragma unroll
  for (int m = 0; m < 8; ++m)
    #pragma unroll
    for (int n = 0; n < 2; ++n) acc[m][n] = (f32x4){0.f, 0.f, 0.f, 0.f};

  // staging: 48 segs (Ah 16, Al 16, Bh 8, Bl 8) over 8 waves -> NJ=6
  const u16* srcp[NJ];
  int loff[NJ];
  #pragma unroll
  for (int j = 0; j < NJ; ++j) {
    int g = j * 8 + wave;
    const u16* gb; int abase, trow, segi;
    if (g < 16)      { gb = Ah; abase = 0;                  trow = m0; segi = g; }
    else if (g < 32) { gb = Al; abase = BM * 32;            trow = m0; segi = g - 16; }
    else if (g < 40) { gb = Bh; abase = 2 * BM * 32;        trow = n0; segi = g - 32; }
    else             { gb = Bl; abase = 2 * BM * 32 + BN * 32; trow = n0; segi = g - 40; }
    srcp[j] = gb + (size_t)(trow + segi * 16 + lrow) * K + (k0 + lcol);
    loff[j] = abase + segi * 512;
  }

  const int aoh0 = (wr * 128 + fr) * 32 + kx;          // + m*512
  const int aol0 = BM * 32 + aoh0;
  const int boh0 = 2 * BM * 32 + (wc * 32 + fr) * 32 + kx;   // + n*512
  const int bol0 = boh0 + BN * 32;

  #define ISSUE2(bufo, j0)                                          \
    { gload_lds16(srcp[j0], S + (bufo) + loff[j0]);  srcp[j0] += 32;   \
      gload_lds16(srcp[j0+1], S + (bufo) + loff[j0+1]); srcp[j0+1] += 32; }

  int curo = 0;
  ISSUE2(curo, 0); ISSUE2(curo, 2); ISSUE2(curo, 4);

  for (int t = 0; t < nst; ++t) {
    const int nxt = curo ^ HALF;
    const bool more = (t + 1 < nst);   // block-uniform
    if (more) { ISSUE2(nxt, 0); WAITVM2(); } else { WAITVM0(); }
    BARRIER();                         // tile t landed for all waves

    short8 bh_[2], bl_[2];
    #pragma unroll
    for (int p = 0; p < 4; ++p) {
      const int m2 = 2 * p;
      short8 a0h = *(const short8*)(S + curo + aoh0 + m2 * 512);
      short8 a0l = *(const short8*)(S + curo + aol0 + m2 * 512);
      short8 a1h = *(const short8*)(S + curo + aoh0 + (m2 + 1) * 512);
      short8 a1l = *(const short8*)(S + curo + aol0 + (m2 + 1) * 512);
      if (p == 0) {
        #pragma unroll
        for (int n = 0; n < 2; ++n) {
          bh_[n] = *(const short8*)(S + curo + boh0 + n * 512);
          bl_[n] = *(const short8*)(S + curo + bol0 + n * 512);
        }
      }
      if (more) {
        if (p == 0) { ISSUE2(nxt, 2); }
        else if (p == 1) { ISSUE2(nxt, 4); }
      }
      BARRIER();
      __builtin_amdgcn_s_setprio(1);
      #pragma unroll
      for (int n = 0; n < 2; ++n) {
        acc[m2][n] = __builtin_amdgcn_mfma_f32_16x16x32_bf16(a0h, bh_[n], acc[m2][n], 0, 0, 0);
        acc[m2][n] = __builtin_amdgcn_mfma_f32_16x16x32_bf16(a0h, bl_[n], acc[m2][n], 0, 0, 0);
        acc[m2][n] = __builtin_amdgcn_mfma_f32_16x16x32_bf16(a0l, bh_[n], acc[m2][n], 0, 0, 0);
        acc[m2+1][n] = __builtin_amdgcn_mfma_f32_16x16x32_bf16(a1h, bh_[n], acc[m2+1][n], 0, 0, 0);
        acc[m2+1][n] = __builtin_amdgcn_mfma_f32_16x16x32_bf16(a1h, bl_[n], acc[m2+1][n], 0, 0, 0);
        acc[m2+1][n] = __builtin_amdgcn_mfma_f32_16x16x32_bf16(a1l, bh_[n], acc[m2+1][n], 0, 0, 0);
      }
      __builtin_amdgcn_s_setprio(0);
      BARRIER();
    }
    curo ^= HALF;
  }
  #undef ISSUE2

  float* base = (n0 < nsplit) ? C0 : C1;
  const int ncol0 = (n0 < nsplit) ? 0 : nsplit;
  float* Cz = base + (size_t)z * M * ldc;
  #pragma unroll
  for (int m = 0; m < 8; ++m) {
    #pragma unroll
    for (int n = 0; n < 2; ++n) {
      int row = m0 + wr * 128 + m * 16 + fq4;
      int col = n0 + wc * 32 + n * 16 + fr - ncol0;
      float* cp = Cz + (size_t)row * ldc + col;
      f32x4 a = acc[m][n];
      cp[0] = a[0];
      cp[(size_t)ldc] = a[1];
      cp[(size_t)2 * ldc] = a[2];
      cp[(size_t)3 * ldc] = a[3];
    }
  }
}

// ---- out = p0 + p1 + p2 + p3 (split-K z=4 reduce, deterministic order) ----
__global__ __launch_bounds__(256) void k_reduce4(const float4* __restrict__ p,
                                                 float4* __restrict__ out, int nvec) {
  int stride = gridDim.x * blockDim.x;
  for (int i = blockIdx.x * blockDim.x + threadIdx.x; i < nvec; i += stride) {
    float4 a = p[i], b = p[nvec + i], c = p[2 * nvec + i], d = p[3 * nvec + i];
    float4 o;
    o.x = ((a.x + b.x) + c.x) + d.x;
    o.y = ((a.y + b.y) + c.y) + d.y;
    o.z = ((a.z + b.z) + c.z) + d.z;
    o.w = ((a.w + b.w) + c.w) + d.w;
    out[i] = o;
  }
}

extern "C" void kernel_launch(void* const* d_in, const int* in_sizes, int n_in,
                              void* d_out, int out_size, void* d_ws, size_t ws_size,
                              hipStream_t stream) {
  const float* x  = (const float*)d_in[0];
  const float* ph = (const float*)d_in[1];
  const float* pi = (const float*)d_in[2];
  const float* pa = (const float*)d_in[3];
  const float* pw = (const float*)d_in[4];
  const float* Wg = (const float*)d_in[5];
  const float* Wu = (const float*)d_in[6];
  const float* Wd = (const float*)d_in[7];
  float* out = (float*)d_out;

  const u32 magic5504 = (u32)(((1ULL << 40) + 5503ULL) / 5504ULL);
  char* ws = (char*)d_ws;

  const size_t szX1 = (size_t)1024 * 3072 * 2;          // 6.29 MB each
  const size_t szWug = (size_t)11008 * 3072 * 2;        // 67.63 MB each (h, l)
  const size_t szUP = (size_t)1024 * 5504 * 4;          // 22.54 MB each
  const size_t fused_need = 1024 + 2 * szX1 + 2 * szWug + 2 * szUP;   // ~193 MB

  if (ws_size >= fused_need) {
    // ---------------- fused up+gate path, both GEMMs on k_gemm8 ----------------
    size_t off = 0;
    float* P = (float*)(ws + off); off += 1024;
    u16* X1h = (u16*)(ws + off); off += szX1;
    u16* X1l = (u16*)(ws + off); off += szX1;
    u16* Wh  = (u16*)(ws + off); off += szWug;   // rows 0..5503 Wu, 5504..11007 Wg
    u16* Wl  = (u16*)(ws + off); off += szWug;
    float* UP   = (float*)(ws + off); off += szUP;
    float* GATE = (float*)(ws + off); off += szUP;
    float* H = UP;   // h overwrites up in place
    // phase-2 aliases (upgate weights dead after fused GEMM):
    u16* X2h = Wh;
    u16* X2l = Wh + (size_t)1024 * 8256;
    float* DPART = (float*)(Wh + (size_t)2 * 1024 * 8256);  // 33.55 <= 33.8 MB tail
    u16* Wdh = Wl;
    u16* Wdl = Wl + (size_t)2048 * 8256;

    k_init<<<1, 64, 0, stream>>>(ph, pi, pa, pw, P);
    k_absmax4<<<1792, 256, 0, stream>>>(x, Wu, Wg, Wd, magic5504, P);
    k_params1<<<1, 64, 0, stream>>>(P);

    k_build1<<<1536 + 16512, 256, 0, stream>>>(x, Wu, Wg, P, X1h, X1l, Wh, Wl);

    // upgate: 8-phase 256x128, grid 4x86 (z=1, full K -> bit-exact), split C-write
    dim3 g1(1024 / 256, 11008 / 128, 1);
    k_gemm8<<<g1, 512, 0, stream>>>(X1h, X1l, Wh, Wl, UP, GATE, 5504, 5504,
                                    1024, 11008, 3072);

    k_h<<<2048, 256, 0, stream>>>(UP, GATE, H, P);
    k_params2<<<1, 64, 0, stream>>>(P);

    k_build2<<<4128 + 8256, 256, 0, stream>>>(H, Wd, P, X2h, X2l, Wdh, Wdl);

    // down: 8-phase 256x128, split-K z=4 -> 256 blocks = 1/CU
    dim3 g2(1024 / 256, 2048 / 128, 4);
    k_gemm8<<<g2, 512, 0, stream>>>(X2h, X2l, Wdh, Wdl, DPART, DPART, 2048, 2048,
                                    1024, 2048, 8256);
    k_reduce4<<<2048, 256, 0, stream>>>((const float4*)DPART, (float4*)out, (1024 * 2048) / 4);
    return;
  }

  // ---------------- fallback: round-6 exact layout, proven kernels ----------------
  size_t off = 0;
  float* P = (float*)(ws + off); off += 1024;
  u16* X1h = (u16*)(ws + off); off += szX1;
  u16* X1l = (u16*)(ws + off); off += szX1;
  u16* Wh  = (u16*)(ws + off); off += (size_t)5504 * 3072 * 2;
  u16* Wl  = (u16*)(ws + off); off += (size_t)5504 * 3072 * 2;
  float* UP   = (float*)(ws + off); off += (size_t)1024 * 5504 * 4;
  float* GATE = (float*)(ws + off); off += (size_t)1024 * 5504 * 4;
  u16* X2h = (u16*)(ws + off); off += (size_t)1024 * 8256 * 2;
  u16* X2l = (u16*)(ws + off); off += (size_t)1024 * 8256 * 2;
  float* H = UP;
  float* DPART = UP;
  if (ws_size < off) return;

  k_init<<<1, 64, 0, stream>>>(ph, pi, pa, pw, P);
  k_absmax4<<<1792, 256, 0, stream>>>(x, Wu, Wg, Wd, magic5504, P);
  k_params1<<<1, 64, 0, stream>>>(P);

  {
    int nch = 1024 * (3072 / 8);
    k_build_x<<<(nch + 255) / 256, 256, 0, stream>>>(x, P, X1h, X1l, 1024, 2048, 1024, 3072, P_SX);
  }
  {
    int nch = 5504 * (3072 / 8);
    k_build_w<<<(nch + 255) / 256, 256, 0, stream>>>(Wu, P, Wh, Wl, 5504, 2048, 1024, 3072, P_SWUP, 2752);
  }
  dim3 g1(1024 / 128, 5504 / 128, 1);
  k_gemm<4, 4><<<g1, 256, 0, stream>>>(X1h, X1l, Wh, Wl, UP, UP, 5504, 5504, 1024, 5504, 3072);
  {
    int nch = 5504 * (3072 / 8);
    k_build_w<<<(nch + 255) / 256, 256, 0, stream>>>(Wg, P, Wh, Wl, 5504, 2048, 1024, 3072, P_SWGATE, 2752);
  }
  k_gemm<4, 4><<<g1, 256, 0, stream>>>(X1h, X1l, Wh, Wl, GATE, GATE, 5504, 5504, 1024, 5504, 3072);

  k_h<<<2048, 256, 0, stream>>>(UP, GATE, H, P);
  k_params2<<<1, 64, 0, stream>>>(P);

  {
    int nch = 1024 * (8256 / 8);
    k_build_x<<<(nch + 255) / 256, 256, 0, stream>>>(H, P, X2h, X2l, 1024, 5504, 2752, 8256, P_SH);
  }
  {
    int nch = 2048 * (8256 / 8);
    k_build_w<<<(nch + 255) / 256, 256, 0, stream>>>(Wd, P, Wh, Wl, 2048, 5504, 2752, 8256, P_SWDOWN, 1024);
  }
  dim3 g2(1024 / 128, 2048 / 128, 4);
  k_gemm<4, 4><<<g2, 256, 0, stream>>>(X2h, X2l, Wh, Wl, DPART, DPART, 2048, 2048, 1024, 2048, 8256);
  k_reduce4<<<2048, 256, 0, stream>>>((const float4*)DPART, (float4*)out, (1024 * 2048) / 4);
}

// Round 13
// 603.076 us; speedup vs baseline: 1.0321x; 1.0321x over previous
//
#include <hip/hip_runtime.h>

typedef __attribute__((ext_vector_type(8))) short short8;
typedef __attribute__((ext_vector_type(4))) float f32x4;
typedef unsigned short u16;
typedef unsigned int u32;
typedef unsigned long long u64;

// params layout (floats)
#define P_WH 0
#define P_WI 2
#define P_WA 4
#define P_WW 6
#define SL_AX 8
#define SL_WUP 12
#define SL_WGATE 16
#define SL_WDOWN 20
#define SL_AH 24
#define P_SX 28
#define P_SWUP 32
#define P_SWGATE 40
#define P_SWDOWN 48
#define P_SH 56

__device__ __forceinline__ u16 f2bf(float f) {
  u32 u = __float_as_uint(f);
  u = (u + 0x7FFFu + ((u >> 16) & 1u)) >> 16;
  return (u16)u;
}
__device__ __forceinline__ float bf2f(u16 h) { return __uint_as_float(((u32)h) << 16); }
__device__ __forceinline__ float fquant(float v, float s) { return rintf(v / s) * s; }

typedef const __attribute__((address_space(1))) u32 gl_u32;
typedef __attribute__((address_space(3))) u32 lds_u32;
__device__ __forceinline__ void gload_lds16(const void* g, void* l) {
  __builtin_amdgcn_global_load_lds((gl_u32*)g, (lds_u32*)l, 16, 0, 0);
}

#define WAITVM8()  asm volatile("s_waitcnt vmcnt(8)" ::: "memory")
#define WAITVM2()  asm volatile("s_waitcnt vmcnt(2)" ::: "memory")
#define WAITVM0()  asm volatile("s_waitcnt vmcnt(0)" ::: "memory")
#define BARRIER()  asm volatile("s_barrier" ::: "memory")

// ---- init: zero absmax slots, compute the four 2-way softmaxes ----
__global__ void k_init(const float* ph, const float* pi, const float* pa,
                       const float* pw, float* P) {
  if (threadIdx.x == 0) {
    u32* U = (u32*)P;
    for (int i = SL_AX; i < SL_AH + 2; ++i) U[i] = 0u;
    const float* src[4] = {ph, pi, pa, pw};
    #pragma unroll
    for (int t = 0; t < 4; ++t) {
      float a = src[t][0], b = src[t][1];
      float mx = fmaxf(a, b);
      float ea = expf(a - mx), eb = expf(b - mx);
      float s = ea + eb;
      P[t * 2 + 0] = ea / s;
      P[t * 2 + 1] = eb / s;
    }
  }
}

// ---- quadrant absmax: branchless, ILP-4, pow2 fast path, block-reduced ----
template <bool POW2>
__device__ __forceinline__ void amax_proc(float4 d, int v, u32 magic, int C,
                                          int r0, int c0,
                                          float& m0, float& m1, float& m2, float& m3) {
  int lin = v << 2;
  int o, c;
  if (POW2) { o = lin >> 11; c = lin & 2047; }
  else {
    o = (int)(((u64)(u32)lin * magic) >> 40);
    c = lin - o * C;
  }
  float mm = fmaxf(fmaxf(fabsf(d.x), fabsf(d.y)), fmaxf(fabsf(d.z), fabsf(d.w)));
  bool rlo = o < r0, clo = c < c0;
  m0 = fmaxf(m0, (rlo && clo) ? mm : 0.f);
  m1 = fmaxf(m1, (rlo && !clo) ? mm : 0.f);
  m2 = fmaxf(m2, (!rlo && clo) ? mm : 0.f);
  m3 = fmaxf(m3, (!rlo && !clo) ? mm : 0.f);
}

template <bool POW2>
__device__ __forceinline__ void absmax_dev(const float4* __restrict__ A4,
                                           int nvec, u32 magic, int C, int r0, int c0,
                                           int slotbase, float* P, int bid, int nb) {
  float m0 = 0.f, m1 = 0.f, m2 = 0.f, m3 = 0.f;
  const int tid = threadIdx.x;
  const int step = nb * 256;
  int v = bid * 256 + tid;
  for (; v + 3 * step < nvec; v += 4 * step) {
    float4 d0 = A4[v];
    float4 d1 = A4[v + step];
    float4 d2 = A4[v + 2 * step];
    float4 d3 = A4[v + 3 * step];
    amax_proc<POW2>(d0, v,            magic, C, r0, c0, m0, m1, m2, m3);
    amax_proc<POW2>(d1, v + step,     magic, C, r0, c0, m0, m1, m2, m3);
    amax_proc<POW2>(d2, v + 2 * step, magic, C, r0, c0, m0, m1, m2, m3);
    amax_proc<POW2>(d3, v + 3 * step, magic, C, r0, c0, m0, m1, m2, m3);
  }
  for (; v < nvec; v += step) {
    float4 d0 = A4[v];
    amax_proc<POW2>(d0, v, magic, C, r0, c0, m0, m1, m2, m3);
  }
  #pragma unroll
  for (int off = 32; off > 0; off >>= 1) {
    m0 = fmaxf(m0, __shfl_xor(m0, off));
    m1 = fmaxf(m1, __shfl_xor(m1, off));
    m2 = fmaxf(m2, __shfl_xor(m2, off));
    m3 = fmaxf(m3, __shfl_xor(m3, off));
  }
  __shared__ float red[16];
  const int wave = tid >> 6;
  if ((tid & 63) == 0) {
    red[wave * 4 + 0] = m0;
    red[wave * 4 + 1] = m1;
    red[wave * 4 + 2] = m2;
    red[wave * 4 + 3] = m3;
  }
  __syncthreads();
  if (tid < 4) {
    float mm = fmaxf(fmaxf(red[tid], red[4 + tid]), fmaxf(red[8 + tid], red[12 + tid]));
    if (mm > 0.f) atomicMax((u32*)P + slotbase + tid, __float_as_uint(mm));
  }
}

__global__ __launch_bounds__(256) void k_absmax4(const float* x, const float* Wu,
                                                 const float* Wg, const float* Wd,
                                                 u32 magic5504, float* P) {
  int b = blockIdx.x;
  if (b < 256)        absmax_dev<true >((const float4*)x,  (1024 * 2048) >> 2, 0, 2048, 1024, 1024, SL_AX,    P, b,        256);
  else if (b < 768)   absmax_dev<true >((const float4*)Wu, (5504 * 2048) >> 2, 0, 2048, 2752, 1024, SL_WUP,   P, b - 256,  512);
  else if (b < 1280)  absmax_dev<true >((const float4*)Wg, (5504 * 2048) >> 2, 0, 2048, 2752, 1024, SL_WGATE, P, b - 768,  512);
  else                absmax_dev<false>((const float4*)Wd, (2048 * 5504) >> 2, magic5504, 5504, 1024, 2752, SL_WDOWN, P, b - 1280, 512);
}

// ---- scales ----
__global__ void k_params1(float* P) {
  if (threadIdx.x != 0 || blockIdx.x != 0) return;
  u32* U = (u32*)P;
  float x00 = __uint_as_float(U[SL_AX + 0]);
  float x01 = __uint_as_float(U[SL_AX + 1]);
  float ax0 = x00;
  float ax1 = fmaxf(x00, x01);
  P[P_SX + 0] = fmaxf(ax0 / 7.f, 1e-8f);
  P[P_SX + 1] = fmaxf(ax0 / 127.f, 1e-8f);
  P[P_SX + 2] = fmaxf(ax1 / 7.f, 1e-8f);
  P[P_SX + 3] = fmaxf(ax1 / 127.f, 1e-8f);
  const int sl[3] = {SL_WUP, SL_WGATE, SL_WDOWN};
  const int sb[3] = {P_SWUP, P_SWGATE, P_SWDOWN};
  #pragma unroll
  for (int t = 0; t < 3; ++t) {
    float q00 = __uint_as_float(U[sl[t] + 0]);
    float q01 = __uint_as_float(U[sl[t] + 1]);
    float q10 = __uint_as_float(U[sl[t] + 2]);
    float q11 = __uint_as_float(U[sl[t] + 3]);
    float a0 = q00;
    float a1 = fmaxf(q00, q10);
    float a2 = fmaxf(q00, q01);
    float a3 = fmaxf(fmaxf(q00, q01), fmaxf(q10, q11));
    float aa[4] = {a0, a1, a2, a3};
    #pragma unroll
    for (int ij = 0; ij < 4; ++ij) {
      P[sb[t] + ij * 2 + 0] = fmaxf(aa[ij] / 7.f, 1e-8f);
      P[sb[t] + ij * 2 + 1] = fmaxf(aa[ij] / 127.f, 1e-8f);
    }
  }
}

__global__ void k_params2(float* P) {
  if (threadIdx.x != 0 || blockIdx.x != 0) return;
  u32* U = (u32*)P;
  float a0 = __uint_as_float(U[SL_AH]);
  float a1 = fmaxf(a0, __uint_as_float(U[SL_AH + 1]));
  P[P_SH + 0] = fmaxf(a0 / 7.f, 1e-8f);
  P[P_SH + 1] = fmaxf(a0 / 127.f, 1e-8f);
  P[P_SH + 2] = fmaxf(a1 / 7.f, 1e-8f);
  P[P_SH + 3] = fmaxf(a1 / 127.f, 1e-8f);
}

// ---- build activation operand element (chunk-XOR pre-swizzled) ----
__device__ __forceinline__ void build_x_one(
    const float* __restrict__ src, const float* __restrict__ P,
    u16* __restrict__ Xh, u16* __restrict__ Xl,
    int Csrc, int cin0, int K, int sbx, int gid, int kpr) {
  int row = gid / kpr;
  int kc_out = (gid - row * kpr) << 3;
  int kc_log = kc_out ^ (((row >> 1) & 3) << 3);
  int i = (kc_log >= cin0) ? 1 : 0;
  int c = kc_log - i * cin0;
  float pin = P[P_WH + i];
  float wa0 = P[P_WA], wa1 = P[P_WA + 1];
  float s4 = P[sbx + i * 2], s8 = P[sbx + i * 2 + 1];
  const float* sp = src + (size_t)row * Csrc + c;
  float v[8];
  *(float4*)&v[0] = *(const float4*)sp;
  *(float4*)&v[4] = *(const float4*)(sp + 4);
  short8 hv, lv;
  #pragma unroll
  for (int e = 0; e < 8; ++e) {
    float val = pin * (wa0 * fquant(v[e], s4) + wa1 * fquant(v[e], s8));
    u16 h = f2bf(val);
    hv[e] = (short)h;
    lv[e] = (short)f2bf(val - bf2f(h));
  }
  size_t off = (size_t)row * K + kc_out;
  *(short8*)(Xh + off) = hv;
  *(short8*)(Xl + off) = lv;
}

// ---- build weight operand element (chunk-XOR pre-swizzled) ----
__device__ __forceinline__ void build_w_one(
    const float* __restrict__ W, const float* __restrict__ P,
    u16* __restrict__ Wh, u16* __restrict__ Wl,
    int Csrc, int cin0, int K, int sbw, int cout0, int rowoff,
    int gid, int kpr) {
  int row = gid / kpr;
  int kc_out = (gid - row * kpr) << 3;
  int kc_log = kc_out ^ (((row >> 1) & 3) << 3);
  int i = (kc_log >= cin0) ? 1 : 0;
  int c = kc_log - i * cin0;
  float wi0 = P[P_WI], wi1 = P[P_WI + 1];
  float ww0 = P[P_WW], ww1 = P[P_WW + 1];
  float s00 = P[sbw + i * 4 + 0];
  float s01 = P[sbw + i * 4 + 1];
  float s10 = P[sbw + i * 4 + 2];
  float s11 = P[sbw + i * 4 + 3];
  float keep0 = (row < cout0) ? wi0 : 0.f;
  const float* sp = W + (size_t)row * Csrc + c;
  float v[8];
  *(float4*)&v[0] = *(const float4*)sp;
  *(float4*)&v[4] = *(const float4*)(sp + 4);
  short8 hv, lv;
  #pragma unroll
  for (int e = 0; e < 8; ++e) {
    float w = v[e];
    float t0 = ww0 * fquant(w, s00) + ww1 * fquant(w, s01);
    float t1 = ww0 * fquant(w, s10) + ww1 * fquant(w, s11);
    float val = keep0 * t0 + wi1 * t1;
    u16 h = f2bf(val);
    hv[e] = (short)h;
    lv[e] = (short)f2bf(val - bf2f(h));
  }
  size_t off = (size_t)(row + rowoff) * K + kc_out;
  *(short8*)(Wh + off) = hv;
  *(short8*)(Wl + off) = lv;
}

// standalone builders (fallback path)
__global__ __launch_bounds__(256) void k_build_x(
    const float* __restrict__ src, const float* __restrict__ P,
    u16* __restrict__ Xh, u16* __restrict__ Xl,
    int rows, int Csrc, int cin0, int K, int sbx) {
  int kpr = K >> 3;
  int nch = rows * kpr;
  int gid = blockIdx.x * blockDim.x + threadIdx.x;
  if (gid >= nch) return;
  build_x_one(src, P, Xh, Xl, Csrc, cin0, K, sbx, gid, kpr);
}

__global__ __launch_bounds__(256) void k_build_w(
    const float* __restrict__ W, const float* __restrict__ P,
    u16* __restrict__ Wh, u16* __restrict__ Wl,
    int R, int Csrc, int cin0, int K, int sbw, int cout0) {
  int kpr = K >> 3;
  int nch = R * kpr;
  int gid = blockIdx.x * blockDim.x + threadIdx.x;
  if (gid >= nch) return;
  build_w_one(W, P, Wh, Wl, Csrc, cin0, K, sbw, cout0, 0, gid, kpr);
}

// merged phase-1 build: x (1536 blocks) + Wu/Wg (16512 blocks)
__global__ __launch_bounds__(256) void k_build1(
    const float* __restrict__ x, const float* __restrict__ Wu,
    const float* __restrict__ Wg, const float* __restrict__ P,
    u16* __restrict__ X1h, u16* __restrict__ X1l,
    u16* __restrict__ Wh, u16* __restrict__ Wl) {
  int bid = blockIdx.x;
  if (bid < 1536) {
    int gid = bid * 256 + threadIdx.x;
    build_x_one(x, P, X1h, X1l, 2048, 1024, 3072, P_SX, gid, 384);
  } else {
    int gid = (bid - 1536) * 256 + threadIdx.x;
    const int nch = 5504 * 384;
    if (gid < nch)
      build_w_one(Wu, P, Wh, Wl, 2048, 1024, 3072, P_SWUP,   2752, 0,    gid,       384);
    else
      build_w_one(Wg, P, Wh, Wl, 2048, 1024, 3072, P_SWGATE, 2752, 5504, gid - nch, 384);
  }
}

// merged phase-2 build: x2 (4128 blocks) + Wd (8256 blocks)
__global__ __launch_bounds__(256) void k_build2(
    const float* __restrict__ H, const float* __restrict__ Wd,
    const float* __restrict__ P,
    u16* __restrict__ X2h, u16* __restrict__ X2l,
    u16* __restrict__ Wdh, u16* __restrict__ Wdl) {
  int bid = blockIdx.x;
  if (bid < 4128) {
    int gid = bid * 256 + threadIdx.x;
    build_x_one(H, P, X2h, X2l, 5504, 2752, 8256, P_SH, gid, 1032);
  } else {
    int gid = (bid - 4128) * 256 + threadIdx.x;
    build_w_one(Wd, P, Wdh, Wdl, 5504, 2752, 8256, P_SWDOWN, 1024, 0, gid, 1032);
  }
}

// ---- h = silu(gate)*up, fused h-absmax. H aliases UP (same-index). ----
__global__ __launch_bounds__(256) void k_h(const float* __restrict__ U_,
                                           const float* __restrict__ G_,
                                           float* __restrict__ H_, float* P) {
  int nvec = (1024 * 5504) >> 2;
  int gstride = gridDim.x * blockDim.x;
  float m0 = 0.f, m1 = 0.f;
  for (int v = blockIdx.x * blockDim.x + threadIdx.x; v < nvec; v += gstride) {
    float4 u = ((const float4*)U_)[v];
    float4 g = ((const float4*)G_)[v];
    float4 h;
    h.x = u.x * (g.x / (1.f + expf(-g.x)));
    h.y = u.y * (g.y / (1.f + expf(-g.y)));
    h.z = u.z * (g.z / (1.f + expf(-g.z)));
    h.w = u.w * (g.w / (1.f + expf(-g.w)));
    ((float4*)H_)[v] = h;
    int c = (v << 2) % 5504;
    float mm = fmaxf(fmaxf(fabsf(h.x), fabsf(h.y)), fmaxf(fabsf(h.z), fabsf(h.w)));
    if (c < 2752) m0 = fmaxf(m0, mm); else m1 = fmaxf(m1, mm);
  }
  #pragma unroll
  for (int off = 32; off > 0; off >>= 1) {
    m0 = fmaxf(m0, __shfl_xor(m0, off));
    m1 = fmaxf(m1, __shfl_xor(m1, off));
  }
  if ((threadIdx.x & 63) == 0) {
    u32* slots = (u32*)P;
    if (m0 > 0.f) atomicMax(slots + SL_AH, __float_as_uint(m0));
    if (m1 > 0.f) atomicMax(slots + SL_AH + 1, __float_as_uint(m1));
  }
}

// ---- bf16x3 MFMA GEMM (proven 2-phase 128x128) — fallback path only ----
template <int MF, int NF>
__global__ __launch_bounds__(256) void k_gemm(
    const u16* __restrict__ Ah, const u16* __restrict__ Al,
    const u16* __restrict__ Bh, const u16* __restrict__ Bl,
    float* __restrict__ C0, float* __restrict__ C1, int nsplit, int ldc,
    int M, int N, int K) {
  constexpr int BM = MF * 32;
  constexpr int BN = NF * 32;
  constexpr int HALF = (2 * BM + 2 * BN) * 32;
  constexpr int nsegA = BM / 16;
  constexpr int nsegB = BN / 16;
  constexpr int NSEG = 2 * nsegA + 2 * nsegB;
  constexpr int NJ = NSEG / 4;
  static_assert(NJ == 8, "vmcnt immediates assume 8 loads per stage");
  __shared__ __align__(16) u16 S[2 * HALF];

  const int tid = threadIdx.x;
  const int wave = tid >> 6;
  const int lane = tid & 63;

  const int gx = gridDim.x;
  const int nwg = gx * gridDim.y;
  const int orig = blockIdx.y * gx + blockIdx.x;
  const int q = nwg >> 3, r = nwg & 7;
  const int xcd = orig & 7, linb = orig >> 3;
  const int swz = (xcd < r ? xcd * (q + 1) : r * (q + 1) + (xcd - r) * q) + linb;
  const int m0 = (swz % gx) * BM;
  const int n0 = (swz / gx) * BN;

  const int St = K >> 5;
  const int Z = gridDim.z;
  const int zb = St / Z, zr = St - zb * Z;
  const int z = blockIdx.z;
  const int nst = zb + ((z < zr) ? 1 : 0);
  const int k0 = (z * zb + ((z < zr) ? z : zr)) << 5;

  const int wr = wave >> 1, wc = wave & 1;
  const int lrow = lane >> 2;
  const int lcol = (lane & 3) << 3;
  const int fr = lane & 15;
  const int fq4 = (lane >> 4) << 2;
  const int kofs = (lane >> 4) << 3;

  f32x4 acc[MF][NF];
  #pragma unroll
  for (int m = 0; m < MF; ++m)
    #pragma unroll
    for (int n = 0; n < NF; ++n) acc[m][n] = (f32x4){0.f, 0.f, 0.f, 0.f};

  const u16* srcp[NJ];
  int loff[NJ];
  #pragma unroll
  for (int j = 0; j < NJ; ++j) {
    int g = j * 4 + wave;
    const u16* gb; int abase, trow, segi;
    if (g < nsegA)               { gb = Ah; abase = 0;                  trow = m0; segi = g; }
    else if (g < 2 * nsegA)      { gb = Al; abase = BM * 32;            trow = m0; segi = g - nsegA; }
    else if (g < 2 * nsegA + nsegB) { gb = Bh; abase = 2 * BM * 32;     trow = n0; segi = g - 2 * nsegA; }
    else                         { gb = Bl; abase = 2 * BM * 32 + BN * 32; trow = n0; segi = g - 2 * nsegA - nsegB; }
    srcp[j] = gb + (size_t)(trow + segi * 16 + lrow) * K + (k0 + lcol);
    loff[j] = abase + segi * 512;
  }

  int aoh[MF], aol[MF], boh[NF], bol[NF];
  #pragma unroll
  for (int m = 0; m < MF; ++m) {
    int rr = wr * (MF * 16) + m * 16 + fr;
    int idx = rr * 32 + (kofs ^ (((rr >> 1) & 3) << 3));
    aoh[m] = idx;
    aol[m] = BM * 32 + idx;
  }
  #pragma unroll
  for (int n = 0; n < NF; ++n) {
    int rr = wc * (NF * 16) + n * 16 + fr;
    int idx = rr * 32 + (kofs ^ (((rr >> 1) & 3) << 3));
    boh[n] = 2 * BM * 32 + idx;
    bol[n] = 2 * BM * 32 + BN * 32 + idx;
  }

  #define STAGE(bufo)                                           \
    { _Pragma("unroll")                                         \
      for (int j = 0; j < NJ; ++j) {                            \
        gload_lds16(srcp[j], S + (bufo) + loff[j]);             \
        srcp[j] += 32;                                          \
      } }

  #define COMPUTE(bufo)                                                         \
    { short8 afh[MF], afl[MF], bfh[NF], bfl[NF];                                \
      _Pragma("unroll")                                                         \
      for (int m = 0; m < MF; ++m) {                                            \
        afh[m] = *(const short8*)(S + (bufo) + aoh[m]);                         \
        afl[m] = *(const short8*)(S + (bufo) + aol[m]);                         \
      }                                                                         \
      _Pragma("unroll")                                                         \
      for (int n = 0; n < NF; ++n) {                                            \
        bfh[n] = *(const short8*)(S + (bufo) + boh[n]);                         \
        bfl[n] = *(const short8*)(S + (bufo) + bol[n]);                         \
      }                                                                         \
      _Pragma("unroll")                                                         \
      for (int m = 0; m < MF; ++m)                                              \
        _Pragma("unroll")                                                       \
        for (int n = 0; n < NF; ++n) {                                          \
          acc[m][n] = __builtin_amdgcn_mfma_f32_16x16x32_bf16(afh[m], bfh[n], acc[m][n], 0, 0, 0); \
          acc[m][n] = __builtin_amdgcn_mfma_f32_16x16x32_bf16(afh[m], bfl[n], acc[m][n], 0, 0, 0); \
          acc[m][n] = __builtin_amdgcn_mfma_f32_16x16x32_bf16(afl[m], bfh[n], acc[m][n], 0, 0, 0); \
        } }

  int curo = 0;
  STAGE(curo);
  for (int t = 0; t + 1 < nst; ++t) {
    STAGE(curo ^ HALF);
    WAITVM8();
    BARRIER();
    COMPUTE(curo);
    BARRIER();
    curo ^= HALF;
  }
  WAITVM0();
  BARRIER();
  COMPUTE(curo);

  #undef STAGE
  #undef COMPUTE

  float* base = (n0 < nsplit) ? C0 : C1;
  const int ncol0 = (n0 < nsplit) ? 0 : nsplit;
  float* Cz = base + (size_t)z * M * ldc;
  #pragma unroll
  for (int m = 0; m < MF; ++m) {
    #pragma unroll
    for (int n = 0; n < NF; ++n) {
      int row = m0 + wr * (MF * 16) + m * 16 + fq4;
      int col = n0 + wc * (NF * 16) + n * 16 + fr - ncol0;
      float* cp = Cz + (size_t)row * ldc + col;
      f32x4 a = acc[m][n];
      cp[0] = a[0];
      cp[(size_t)ldc] = a[1];
      cp[(size_t)2 * ldc] = a[2];
      cp[(size_t)3 * ldc] = a[3];
    }
  }
}

// ---- 8-phase bf16x3 GEMM, BM=256 x BN=256, 8 waves (2m x 4n, wave=128x64),
//      128KB LDS (1 blk/CU), NJ=8. Sync skeleton identical to proven r11:
//      pre{issue2, vmcnt(2), bar} + 4 phases{ds_read, issue2(p0..p2), bar,
//      setprio1, 24 MFMA, setprio0, bar}. vmcnt never 0 in-loop.
//      CMODE 0: per-element col split at nsplit (C0 ld=ldc | C1). Z must be 1.
//      CMODE 1: z-split partials, z<4 -> C0+z*M*ldc else C1+(z-4)*M*ldc. ----
template <int CMODE>
__global__ __launch_bounds__(512) void k_gemm8w(
    const u16* __restrict__ Ah, const u16* __restrict__ Al,
    const u16* __restrict__ Bh, const u16* __restrict__ Bl,
    float* __restrict__ C0, float* __restrict__ C1, int nsplit, int ldc,
    int M, int N, int K) {
  constexpr int BM = 256, BN = 256;
  constexpr int HALF = (2 * BM + 2 * BN) * 32;   // 32768 u16 = 64 KB
  constexpr int NJ = 8;
  __shared__ __align__(16) u16 S[2 * HALF];      // 128 KB

  const int tid = threadIdx.x;
  const int wave = tid >> 6;   // 0..7
  const int lane = tid & 63;

  const int gx = gridDim.x;
  const int nwg = gx * gridDim.y;
  const int orig = blockIdx.y * gx + blockIdx.x;
  const int q = nwg >> 3, r = nwg & 7;
  const int xcd = orig & 7, linb = orig >> 3;
  const int swz = (xcd < r ? xcd * (q + 1) : r * (q + 1) + (xcd - r) * q) + linb;
  const int m0 = (swz % gx) * BM;
  const int n0 = (swz / gx) * BN;

  const int St = K >> 5;
  const int Z = gridDim.z;
  const int zb = St / Z, zr = St - zb * Z;
  const int z = blockIdx.z;
  const int nst = zb + ((z < zr) ? 1 : 0);
  const int k0 = (z * zb + ((z < zr) ? z : zr)) << 5;

  const int wr = wave >> 2;    // 0..1 (row half)
  const int wc = wave & 3;     // 0..3 (col quarter, 64 cols each)
  const int lrow = lane >> 2;
  const int lcol = (lane & 3) << 3;
  const int fr = lane & 15;
  const int fq4 = (lane >> 4) << 2;
  const int kofs = (lane >> 4) << 3;
  const int kx = kofs ^ (((fr >> 1) & 3) << 3);  // row-XOR reduces to fr-only (m0,n0,wave terms mod 8 == 0)

  f32x4 acc[8][4];
  #pragma unroll
  for (int m = 0; m < 8; ++m)
    #pragma unroll
    for (int n = 0; n < 4; ++n) acc[m][n] = (f32x4){0.f, 0.f, 0.f, 0.f};

  // staging: 64 segs (Ah 16, Al 16, Bh 16, Bl 16) over 8 waves -> NJ=8
  const u16* srcp[NJ];
  int loff[NJ];
  #pragma unroll
  for (int j = 0; j < NJ; ++j) {
    int g = j * 8 + wave;
    const u16* gb; int abase, trow, segi;
    if (g < 16)      { gb = Ah; abase = 0;         trow = m0; segi = g; }
    else if (g < 32) { gb = Al; abase = 8192;      trow = m0; segi = g - 16; }
    else if (g < 48) { gb = Bh; abase = 16384;     trow = n0; segi = g - 32; }
    else             { gb = Bl; abase = 24576;     trow = n0; segi = g - 48; }
    srcp[j] = gb + (size_t)(trow + segi * 16 + lrow) * K + (k0 + lcol);
    loff[j] = abase + segi * 512;
  }

  const int aoh0 = (wr * 128 + fr) * 32 + kx;           // + m*512
  const int aol0 = 8192 + aoh0;
  const int boh0 = 16384 + (wc * 64 + fr) * 32 + kx;    // + n*512
  const int bol0 = boh0 + 8192;

  #define ISSUE2(bufo, j0)                                             \
    { gload_lds16(srcp[j0], S + (bufo) + loff[j0]);  srcp[j0] += 32;   \
      gload_lds16(srcp[j0+1], S + (bufo) + loff[j0+1]); srcp[j0+1] += 32; }

  int curo = 0;
  ISSUE2(curo, 0); ISSUE2(curo, 2); ISSUE2(curo, 4); ISSUE2(curo, 6);

  for (int t = 0; t < nst; ++t) {
    const int nxt = curo ^ HALF;
    const bool more = (t + 1 < nst);   // block-uniform
    if (more) { ISSUE2(nxt, 0); WAITVM2(); } else { WAITVM0(); }
    BARRIER();                         // tile t landed for all waves

    #pragma unroll
    for (int p = 0; p < 4; ++p) {
      const int m2 = 2 * p;
      short8 a0h = *(const short8*)(S + curo + aoh0 + m2 * 512);
      short8 a0l = *(const short8*)(S + curo + aol0 + m2 * 512);
      short8 a1h = *(const short8*)(S + curo + aoh0 + (m2 + 1) * 512);
      short8 a1l = *(const short8*)(S + curo + aol0 + (m2 + 1) * 512);
      if (more) {
        if (p == 0) { ISSUE2(nxt, 2); }
        else if (p == 1) { ISSUE2(nxt, 4); }
        else if (p == 2) { ISSUE2(nxt, 6); }
      }
      BARRIER();
      __builtin_amdgcn_s_setprio(1);
      #pragma unroll
      for (int n = 0; n < 4; ++n) {
        short8 bh = *(const short8*)(S + curo + boh0 + n * 512);
        short8 bl = *(const short8*)(S + curo + bol0 + n * 512);
        acc[m2][n] = __builtin_amdgcn_mfma_f32_16x16x32_bf16(a0h, bh, acc[m2][n], 0, 0, 0);
        acc[m2][n] = __builtin_amdgcn_mfma_f32_16x16x32_bf16(a0h, bl, acc[m2][n], 0, 0, 0);
        acc[m2][n] = __builtin_amdgcn_mfma_f32_16x16x32_bf16(a0l, bh, acc[m2][n], 0, 0, 0);
        acc[m2+1][n] = __builtin_amdgcn_mfma_f32_16x16x32_bf16(a1h, bh, acc[m2+1][n], 0, 0, 0);
        acc[m2+1][n] = __builtin_amdgcn_mfma_f32_16x16x32_bf16(a1h, bl, acc[m2+1][n], 0, 0, 0);
        acc[m2+1][n] = __builtin_amdgcn_mfma_f32_16x16x32_bf16(a1l, bh, acc[m2+1][n], 0, 0, 0);
      }
      __builtin_amdgcn_s_setprio(0);
      BARRIER();
    }
    curo ^= HALF;
  }
  #undef ISSUE2

  if (CMODE == 0) {
    // per-element column split (UP | GATE seam may cross a 256-wide tile)
    #pragma unroll
    for (int m = 0; m < 8; ++m) {
      #pragma unroll
      for (int n = 0; n < 4; ++n) {
        int row = m0 + wr * 128 + m * 16 + fq4;
        int col = n0 + wc * 64 + n * 16 + fr;
        float* base = (col < nsplit) ? C0 : C1;
        int cw = (col < nsplit) ? col : col - nsplit;
        float* cp = base + (size_t)row * ldc + cw;
        f32x4 a = acc[m][n];
        cp[0] = a[0];
        cp[(size_t)ldc] = a[1];
        cp[(size_t)2 * ldc] = a[2];
        cp[(size_t)3 * ldc] = a[3];
      }
    }
  } else {
    float* Cz = (z < 4) ? (C0 + (size_t)z * M * ldc) : (C1 + (size_t)(z - 4) * M * ldc);
    #pragma unroll
    for (int m = 0; m < 8; ++m) {
      #pragma unroll
      for (int n = 0; n < 4; ++n) {
        int row = m0 + wr * 128 + m * 16 + fq4;
        int col = n0 + wc * 64 + n * 16 + fr;
        float* cp = Cz + (size_t)row * ldc + col;
        f32x4 a = acc[m][n];
        cp[0] = a[0];
        cp[(size_t)ldc] = a[1];
        cp[(size_t)2 * ldc] = a[2];
        cp[(size_t)3 * ldc] = a[3];
      }
    }
  }
}

// ---- out = sum of 8 partials (4 at p0, 4 at p1), fixed order ----
__global__ __launch_bounds__(256) void k_reduce8(const float4* __restrict__ p0,
                                                 const float4* __restrict__ p1,
                                                 float4* __restrict__ out, int nvec) {
  int stride = gridDim.x * blockDim.x;
  for (int i = blockIdx.x * blockDim.x + threadIdx.x; i < nvec; i += stride) {
    float4 s = p0[i];
    #pragma unroll
    for (int zz = 1; zz < 4; ++zz) {
      float4 b = p0[(size_t)zz * nvec + i];
      s.x += b.x; s.y += b.y; s.z += b.z; s.w += b.w;
    }
    #pragma unroll
    for (int zz = 0; zz < 4; ++zz) {
      float4 b = p1[(size_t)zz * nvec + i];
      s.x += b.x; s.y += b.y; s.z += b.z; s.w += b.w;
    }
    out[i] = s;
  }
}

// ---- out = p0+p1+p2+p3 (fallback reduce) ----
__global__ __launch_bounds__(256) void k_reduce4(const float4* __restrict__ p,
                                                 float4* __restrict__ out, int nvec) {
  int stride = gridDim.x * blockDim.x;
  for (int i = blockIdx.x * blockDim.x + threadIdx.x; i < nvec; i += stride) {
    float4 a = p[i], b = p[nvec + i], c = p[2 * nvec + i], d = p[3 * nvec + i];
    float4 o;
    o.x = ((a.x + b.x) + c.x) + d.x;
    o.y = ((a.y + b.y) + c.y) + d.y;
    o.z = ((a.z + b.z) + c.z) + d.z;
    o.w = ((a.w + b.w) + c.w) + d.w;
    out[i] = o;
  }
}

extern "C" void kernel_launch(void* const* d_in, const int* in_sizes, int n_in,
                              void* d_out, int out_size, void* d_ws, size_t ws_size,
                              hipStream_t stream) {
  const float* x  = (const float*)d_in[0];
  const float* ph = (const float*)d_in[1];
  const float* pi = (const float*)d_in[2];
  const float* pa = (const float*)d_in[3];
  const float* pw = (const float*)d_in[4];
  const float* Wg = (const float*)d_in[5];
  const float* Wu = (const float*)d_in[6];
  const float* Wd = (const float*)d_in[7];
  float* out = (float*)d_out;

  const u32 magic5504 = (u32)(((1ULL << 40) + 5503ULL) / 5504ULL);
  char* ws = (char*)d_ws;

  const size_t szX1 = (size_t)1024 * 3072 * 2;          // 6.29 MB each
  const size_t szWug = (size_t)11008 * 3072 * 2;        // 67.63 MB each (h, l)
  const size_t szUP = (size_t)1024 * 5504 * 4;          // 22.54 MB each
  const size_t fused_need = 1024 + 2 * szX1 + 2 * szWug + 2 * szUP;   // ~193 MB

  if (ws_size >= fused_need) {
    // ---------------- fused up+gate path, both GEMMs on k_gemm8w ----------------
    size_t off = 0;
    float* P = (float*)(ws + off); off += 1024;
    u16* X1h = (u16*)(ws + off); off += szX1;
    u16* X1l = (u16*)(ws + off); off += szX1;
    u16* Wh  = (u16*)(ws + off); off += szWug;   // rows 0..5503 Wu, 5504..11007 Wg
    u16* Wl  = (u16*)(ws + off); off += szWug;
    float* UP   = (float*)(ws + off); off += szUP;
    float* GATE = (float*)(ws + off); off += szUP;
    float* H = UP;   // h overwrites up in place
    // phase-2 aliases (upgate weights dead after fused GEMM):
    u16* X2h = Wh;
    u16* X2l = Wh + (size_t)1024 * 8256;
    float* DPz1 = (float*)(Wh + (size_t)2 * 1024 * 8256);  // 33.55 <= 33.81 MB tail
    float* DPz0 = UP;                                      // UP+GATE: 33.55 <= 45.1 MB
    u16* Wdh = Wl;
    u16* Wdl = Wl + (size_t)2048 * 8256;

    k_init<<<1, 64, 0, stream>>>(ph, pi, pa, pw, P);
    k_absmax4<<<1792, 256, 0, stream>>>(x, Wu, Wg, Wd, magic5504, P);
    k_params1<<<1, 64, 0, stream>>>(P);

    k_build1<<<1536 + 16512, 256, 0, stream>>>(x, Wu, Wg, P, X1h, X1l, Wh, Wl);

    // upgate: 8-phase 256x256, grid 4x43 = 172 blocks (single fill), z=1
    // full-K per output -> bit-exact; per-element col split at 5504
    dim3 g1(1024 / 256, 11008 / 256, 1);
    k_gemm8w<0><<<g1, 512, 0, stream>>>(X1h, X1l, Wh, Wl, UP, GATE, 5504, 5504,
                                        1024, 11008, 3072);

    k_h<<<2048, 256, 0, stream>>>(UP, GATE, H, P);
    k_params2<<<1, 64, 0, stream>>>(P);

    k_build2<<<4128 + 8256, 256, 0, stream>>>(H, Wd, P, X2h, X2l, Wdh, Wdl);

    // down: 8-phase 256x256, split-K z=8 -> 4*8*8 = 256 blocks = exactly 1/CU
    // (safe: no fake_quant downstream); partials split across DPz0/DPz1
    dim3 g2(1024 / 256, 2048 / 256, 8);
    k_gemm8w<1><<<g2, 512, 0, stream>>>(X2h, X2l, Wdh, Wdl, DPz0, DPz1, 2048, 2048,
                                        1024, 2048, 8256);
    k_reduce8<<<2048, 256, 0, stream>>>((const float4*)DPz0, (const float4*)DPz1,
                                        (float4*)out, (1024 * 2048) / 4);
    return;
  }

  // ---------------- fallback: round-6 exact layout, proven kernels ----------------
  size_t off = 0;
  float* P = (float*)(ws + off); off += 1024;
  u16* X1h = (u16*)(ws + off); off += szX1;
  u16* X1l = (u16*)(ws + off); off += szX1;
  u16* Wh  = (u16*)(ws + off); off += (size_t)5504 * 3072 * 2;
  u16* Wl  = (u16*)(ws + off); off += (size_t)5504 * 3072 * 2;
  float* UP   = (float*)(ws + off); off += (size_t)1024 * 5504 * 4;
  float* GATE = (float*)(ws + off); off += (size_t)1024 * 5504 * 4;
  u16* X2h = (u16*)(ws + off); off += (size_t)1024 * 8256 * 2;
  u16* X2l = (u16*)(ws + off); off += (size_t)1024 * 8256 * 2;
  float* H = UP;
  float* DPART = UP;
  if (ws_size < off) return;

  k_init<<<1, 64, 0, stream>>>(ph, pi, pa, pw, P);
  k_absmax4<<<1792, 256, 0, stream>>>(x, Wu, Wg, Wd, magic5504, P);
  k_params1<<<1, 64, 0, stream>>>(P);

  {
    int nch = 1024 * (3072 / 8);
    k_build_x<<<(nch + 255) / 256, 256, 0, stream>>>(x, P, X1h, X1l, 1024, 2048, 1024, 3072, P_SX);
  }
  {
    int nch = 5504 * (3072 / 8);
    k_build_w<<<(nch + 255) / 256, 256, 0, stream>>>(Wu, P, Wh, Wl, 5504, 2048, 1024, 3072, P_SWUP, 2752);
  }
  dim3 g1(1024 / 128, 5504 / 128, 1);
  k_gemm<4, 4><<<g1, 256, 0, stream>>>(X1h, X1l, Wh, Wl, UP, UP, 5504, 5504, 1024, 5504, 3072);
  {
    int nch = 5504 * (3072 / 8);
    k_build_w<<<(nch + 255) / 256, 256, 0, stream>>>(Wg, P, Wh, Wl, 5504, 2048, 1024, 3072, P_SWGATE, 2752);
  }
  k_gemm<4, 4><<<g1, 256, 0, stream>>>(X1h, X1l, Wh, Wl, GATE, GATE, 5504, 5504, 1024, 5504, 3072);

  k_h<<<2048, 256, 0, stream>>>(UP, GATE, H, P);
  k_params2<<<1, 64, 0, stream>>>(P);

  {
    int nch = 1024 * (8256 / 8);
    k_build_x<<<(nch + 255) / 256, 256, 0, stream>>>(H, P, X2h, X2l, 1024, 5504, 2752, 8256, P_SH);
  }
  {
    int nch = 2048 * (8256 / 8);
    k_build_w<<<(nch + 255) / 256, 256, 0, stream>>>(Wd, P, Wh, Wl, 2048, 5504, 2752, 8256, P_SWDOWN, 1024);
  }
  dim3 g2(1024 / 128, 2048 / 128, 4);
  k_gemm<4, 4><<<g2, 256, 0, stream>>>(X2h, X2l, Wh, Wl, DPART, DPART, 2048, 2048, 1024, 2048, 8256);
  k_reduce4<<<2048, 256, 0, stream>>>((const float4*)DPART, (float4*)out, (1024 * 2048) / 4);
}

// Round 14
// 576.133 us; speedup vs baseline: 1.0804x; 1.0468x over previous
//
#include <hip/hip_runtime.h>

typedef __attribute__((ext_vector_type(8))) short short8;
typedef __attribute__((ext_vector_type(4))) float f32x4;
typedef unsigned short u16;
typedef unsigned int u32;
typedef unsigned long long u64;

// params layout (floats)
#define P_WH 0
#define P_WI 2
#define P_WA 4
#define P_WW 6
#define SL_AX 8
#define SL_WUP 12
#define SL_WGATE 16
#define SL_WDOWN 20
#define SL_AH 24
#define P_SX 28
#define P_SWUP 32
#define P_SWGATE 40
#define P_SWDOWN 48
#define P_SH 56

__device__ __forceinline__ u16 f2bf(float f) {
  u32 u = __float_as_uint(f);
  u = (u + 0x7FFFu + ((u >> 16) & 1u)) >> 16;
  return (u16)u;
}
__device__ __forceinline__ float bf2f(u16 h) { return __uint_as_float(((u32)h) << 16); }
__device__ __forceinline__ float fquant(float v, float s) { return rintf(v / s) * s; }

typedef const __attribute__((address_space(1))) u32 gl_u32;
typedef __attribute__((address_space(3))) u32 lds_u32;
__device__ __forceinline__ void gload_lds16(const void* g, void* l) {
  __builtin_amdgcn_global_load_lds((gl_u32*)g, (lds_u32*)l, 16, 0, 0);
}

#define WAITVM8()  asm volatile("s_waitcnt vmcnt(8)" ::: "memory")
#define WAITVM2()  asm volatile("s_waitcnt vmcnt(2)" ::: "memory")
#define WAITVM0()  asm volatile("s_waitcnt vmcnt(0)" ::: "memory")
#define BARRIER()  asm volatile("s_barrier" ::: "memory")

// ---- init: zero absmax slots, compute the four 2-way softmaxes ----
__global__ void k_init(const float* ph, const float* pi, const float* pa,
                       const float* pw, float* P) {
  if (threadIdx.x == 0) {
    u32* U = (u32*)P;
    for (int i = SL_AX; i < SL_AH + 2; ++i) U[i] = 0u;
    const float* src[4] = {ph, pi, pa, pw};
    #pragma unroll
    for (int t = 0; t < 4; ++t) {
      float a = src[t][0], b = src[t][1];
      float mx = fmaxf(a, b);
      float ea = expf(a - mx), eb = expf(b - mx);
      float s = ea + eb;
      P[t * 2 + 0] = ea / s;
      P[t * 2 + 1] = eb / s;
    }
  }
}

// ---- quadrant absmax: branchless, ILP-4, pow2 fast path, block-reduced ----
template <bool POW2>
__device__ __forceinline__ void amax_proc(float4 d, int v, u32 magic, int C,
                                          int r0, int c0,
                                          float& m0, float& m1, float& m2, float& m3) {
  int lin = v << 2;
  int o, c;
  if (POW2) { o = lin >> 11; c = lin & 2047; }
  else {
    o = (int)(((u64)(u32)lin * magic) >> 40);
    c = lin - o * C;
  }
  float mm = fmaxf(fmaxf(fabsf(d.x), fabsf(d.y)), fmaxf(fabsf(d.z), fabsf(d.w)));
  bool rlo = o < r0, clo = c < c0;
  m0 = fmaxf(m0, (rlo && clo) ? mm : 0.f);
  m1 = fmaxf(m1, (rlo && !clo) ? mm : 0.f);
  m2 = fmaxf(m2, (!rlo && clo) ? mm : 0.f);
  m3 = fmaxf(m3, (!rlo && !clo) ? mm : 0.f);
}

template <bool POW2>
__device__ __forceinline__ void absmax_dev(const float4* __restrict__ A4,
                                           int nvec, u32 magic, int C, int r0, int c0,
                                           int slotbase, float* P, int bid, int nb) {
  float m0 = 0.f, m1 = 0.f, m2 = 0.f, m3 = 0.f;
  const int tid = threadIdx.x;
  const int step = nb * 256;
  int v = bid * 256 + tid;
  for (; v + 3 * step < nvec; v += 4 * step) {
    float4 d0 = A4[v];
    float4 d1 = A4[v + step];
    float4 d2 = A4[v + 2 * step];
    float4 d3 = A4[v + 3 * step];
    amax_proc<POW2>(d0, v,            magic, C, r0, c0, m0, m1, m2, m3);
    amax_proc<POW2>(d1, v + step,     magic, C, r0, c0, m0, m1, m2, m3);
    amax_proc<POW2>(d2, v + 2 * step, magic, C, r0, c0, m0, m1, m2, m3);
    amax_proc<POW2>(d3, v + 3 * step, magic, C, r0, c0, m0, m1, m2, m3);
  }
  for (; v < nvec; v += step) {
    float4 d0 = A4[v];
    amax_proc<POW2>(d0, v, magic, C, r0, c0, m0, m1, m2, m3);
  }
  #pragma unroll
  for (int off = 32; off > 0; off >>= 1) {
    m0 = fmaxf(m0, __shfl_xor(m0, off));
    m1 = fmaxf(m1, __shfl_xor(m1, off));
    m2 = fmaxf(m2, __shfl_xor(m2, off));
    m3 = fmaxf(m3, __shfl_xor(m3, off));
  }
  __shared__ float red[16];
  const int wave = tid >> 6;
  if ((tid & 63) == 0) {
    red[wave * 4 + 0] = m0;
    red[wave * 4 + 1] = m1;
    red[wave * 4 + 2] = m2;
    red[wave * 4 + 3] = m3;
  }
  __syncthreads();
  if (tid < 4) {
    float mm = fmaxf(fmaxf(red[tid], red[4 + tid]), fmaxf(red[8 + tid], red[12 + tid]));
    if (mm > 0.f) atomicMax((u32*)P + slotbase + tid, __float_as_uint(mm));
  }
}

__global__ __launch_bounds__(256) void k_absmax4(const float* x, const float* Wu,
                                                 const float* Wg, const float* Wd,
                                                 u32 magic5504, float* P) {
  int b = blockIdx.x;
  if (b < 256)        absmax_dev<true >((const float4*)x,  (1024 * 2048) >> 2, 0, 2048, 1024, 1024, SL_AX,    P, b,        256);
  else if (b < 768)   absmax_dev<true >((const float4*)Wu, (5504 * 2048) >> 2, 0, 2048, 2752, 1024, SL_WUP,   P, b - 256,  512);
  else if (b < 1280)  absmax_dev<true >((const float4*)Wg, (5504 * 2048) >> 2, 0, 2048, 2752, 1024, SL_WGATE, P, b - 768,  512);
  else                absmax_dev<false>((const float4*)Wd, (2048 * 5504) >> 2, magic5504, 5504, 1024, 2752, SL_WDOWN, P, b - 1280, 512);
}

// ---- scales ----
__global__ void k_params1(float* P) {
  if (threadIdx.x != 0 || blockIdx.x != 0) return;
  u32* U = (u32*)P;
  float x00 = __uint_as_float(U[SL_AX + 0]);
  float x01 = __uint_as_float(U[SL_AX + 1]);
  float ax0 = x00;
  float ax1 = fmaxf(x00, x01);
  P[P_SX + 0] = fmaxf(ax0 / 7.f, 1e-8f);
  P[P_SX + 1] = fmaxf(ax0 / 127.f, 1e-8f);
  P[P_SX + 2] = fmaxf(ax1 / 7.f, 1e-8f);
  P[P_SX + 3] = fmaxf(ax1 / 127.f, 1e-8f);
  const int sl[3] = {SL_WUP, SL_WGATE, SL_WDOWN};
  const int sb[3] = {P_SWUP, P_SWGATE, P_SWDOWN};
  #pragma unroll
  for (int t = 0; t < 3; ++t) {
    float q00 = __uint_as_float(U[sl[t] + 0]);
    float q01 = __uint_as_float(U[sl[t] + 1]);
    float q10 = __uint_as_float(U[sl[t] + 2]);
    float q11 = __uint_as_float(U[sl[t] + 3]);
    float a0 = q00;
    float a1 = fmaxf(q00, q10);
    float a2 = fmaxf(q00, q01);
    float a3 = fmaxf(fmaxf(q00, q01), fmaxf(q10, q11));
    float aa[4] = {a0, a1, a2, a3};
    #pragma unroll
    for (int ij = 0; ij < 4; ++ij) {
      P[sb[t] + ij * 2 + 0] = fmaxf(aa[ij] / 7.f, 1e-8f);
      P[sb[t] + ij * 2 + 1] = fmaxf(aa[ij] / 127.f, 1e-8f);
    }
  }
}

__global__ void k_params2(float* P) {
  if (threadIdx.x != 0 || blockIdx.x != 0) return;
  u32* U = (u32*)P;
  float a0 = __uint_as_float(U[SL_AH]);
  float a1 = fmaxf(a0, __uint_as_float(U[SL_AH + 1]));
  P[P_SH + 0] = fmaxf(a0 / 7.f, 1e-8f);
  P[P_SH + 1] = fmaxf(a0 / 127.f, 1e-8f);
  P[P_SH + 2] = fmaxf(a1 / 7.f, 1e-8f);
  P[P_SH + 3] = fmaxf(a1 / 127.f, 1e-8f);
}

// ---- build activation operand element (chunk-XOR pre-swizzled) ----
__device__ __forceinline__ void build_x_one(
    const float* __restrict__ src, const float* __restrict__ P,
    u16* __restrict__ Xh, u16* __restrict__ Xl,
    int Csrc, int cin0, int K, int sbx, int gid, int kpr) {
  int row = gid / kpr;
  int kc_out = (gid - row * kpr) << 3;
  int kc_log = kc_out ^ (((row >> 1) & 3) << 3);
  int i = (kc_log >= cin0) ? 1 : 0;
  int c = kc_log - i * cin0;
  float pin = P[P_WH + i];
  float wa0 = P[P_WA], wa1 = P[P_WA + 1];
  float s4 = P[sbx + i * 2], s8 = P[sbx + i * 2 + 1];
  const float* sp = src + (size_t)row * Csrc + c;
  float v[8];
  *(float4*)&v[0] = *(const float4*)sp;
  *(float4*)&v[4] = *(const float4*)(sp + 4);
  short8 hv, lv;
  #pragma unroll
  for (int e = 0; e < 8; ++e) {
    float val = pin * (wa0 * fquant(v[e], s4) + wa1 * fquant(v[e], s8));
    u16 h = f2bf(val);
    hv[e] = (short)h;
    lv[e] = (short)f2bf(val - bf2f(h));
  }
  size_t off = (size_t)row * K + kc_out;
  *(short8*)(Xh + off) = hv;
  *(short8*)(Xl + off) = lv;
}

// ---- build weight operand element (chunk-XOR pre-swizzled) ----
__device__ __forceinline__ void build_w_one(
    const float* __restrict__ W, const float* __restrict__ P,
    u16* __restrict__ Wh, u16* __restrict__ Wl,
    int Csrc, int cin0, int K, int sbw, int cout0, int rowoff,
    int gid, int kpr) {
  int row = gid / kpr;
  int kc_out = (gid - row * kpr) << 3;
  int kc_log = kc_out ^ (((row >> 1) & 3) << 3);
  int i = (kc_log >= cin0) ? 1 : 0;
  int c = kc_log - i * cin0;
  float wi0 = P[P_WI], wi1 = P[P_WI + 1];
  float ww0 = P[P_WW], ww1 = P[P_WW + 1];
  float s00 = P[sbw + i * 4 + 0];
  float s01 = P[sbw + i * 4 + 1];
  float s10 = P[sbw + i * 4 + 2];
  float s11 = P[sbw + i * 4 + 3];
  float keep0 = (row < cout0) ? wi0 : 0.f;
  const float* sp = W + (size_t)row * Csrc + c;
  float v[8];
  *(float4*)&v[0] = *(const float4*)sp;
  *(float4*)&v[4] = *(const float4*)(sp + 4);
  short8 hv, lv;
  #pragma unroll
  for (int e = 0; e < 8; ++e) {
    float w = v[e];
    float t0 = ww0 * fquant(w, s00) + ww1 * fquant(w, s01);
    float t1 = ww0 * fquant(w, s10) + ww1 * fquant(w, s11);
    float val = keep0 * t0 + wi1 * t1;
    u16 h = f2bf(val);
    hv[e] = (short)h;
    lv[e] = (short)f2bf(val - bf2f(h));
  }
  size_t off = (size_t)(row + rowoff) * K + kc_out;
  *(short8*)(Wh + off) = hv;
  *(short8*)(Wl + off) = lv;
}

// standalone builders (fallback path)
__global__ __launch_bounds__(256) void k_build_x(
    const float* __restrict__ src, const float* __restrict__ P,
    u16* __restrict__ Xh, u16* __restrict__ Xl,
    int rows, int Csrc, int cin0, int K, int sbx) {
  int kpr = K >> 3;
  int nch = rows * kpr;
  int gid = blockIdx.x * blockDim.x + threadIdx.x;
  if (gid >= nch) return;
  build_x_one(src, P, Xh, Xl, Csrc, cin0, K, sbx, gid, kpr);
}

__global__ __launch_bounds__(256) void k_build_w(
    const float* __restrict__ W, const float* __restrict__ P,
    u16* __restrict__ Wh, u16* __restrict__ Wl,
    int R, int Csrc, int cin0, int K, int sbw, int cout0) {
  int kpr = K >> 3;
  int nch = R * kpr;
  int gid = blockIdx.x * blockDim.x + threadIdx.x;
  if (gid >= nch) return;
  build_w_one(W, P, Wh, Wl, Csrc, cin0, K, sbw, cout0, 0, gid, kpr);
}

// merged phase-1 build: x (1536 blocks) + Wu/Wg (16512 blocks)
__global__ __launch_bounds__(256) void k_build1(
    const float* __restrict__ x, const float* __restrict__ Wu,
    const float* __restrict__ Wg, const float* __restrict__ P,
    u16* __restrict__ X1h, u16* __restrict__ X1l,
    u16* __restrict__ Wh, u16* __restrict__ Wl) {
  int bid = blockIdx.x;
  if (bid < 1536) {
    int gid = bid * 256 + threadIdx.x;
    build_x_one(x, P, X1h, X1l, 2048, 1024, 3072, P_SX, gid, 384);
  } else {
    int gid = (bid - 1536) * 256 + threadIdx.x;
    const int nch = 5504 * 384;
    if (gid < nch)
      build_w_one(Wu, P, Wh, Wl, 2048, 1024, 3072, P_SWUP,   2752, 0,    gid,       384);
    else
      build_w_one(Wg, P, Wh, Wl, 2048, 1024, 3072, P_SWGATE, 2752, 5504, gid - nch, 384);
  }
}

// merged phase-2 build: x2 (4128 blocks) + Wd (8256 blocks)
__global__ __launch_bounds__(256) void k_build2(
    const float* __restrict__ H, const float* __restrict__ Wd,
    const float* __restrict__ P,
    u16* __restrict__ X2h, u16* __restrict__ X2l,
    u16* __restrict__ Wdh, u16* __restrict__ Wdl) {
  int bid = blockIdx.x;
  if (bid < 4128) {
    int gid = bid * 256 + threadIdx.x;
    build_x_one(H, P, X2h, X2l, 5504, 2752, 8256, P_SH, gid, 1032);
  } else {
    int gid = (bid - 4128) * 256 + threadIdx.x;
    build_w_one(Wd, P, Wdh, Wdl, 5504, 2752, 8256, P_SWDOWN, 1024, 0, gid, 1032);
  }
}

// ---- h = silu(gate)*up, fused h-absmax. H aliases UP (same-index). ----
__global__ __launch_bounds__(256) void k_h(const float* __restrict__ U_,
                                           const float* __restrict__ G_,
                                           float* __restrict__ H_, float* P) {
  int nvec = (1024 * 5504) >> 2;
  int gstride = gridDim.x * blockDim.x;
  float m0 = 0.f, m1 = 0.f;
  for (int v = blockIdx.x * blockDim.x + threadIdx.x; v < nvec; v += gstride) {
    float4 u = ((const float4*)U_)[v];
    float4 g = ((const float4*)G_)[v];
    float4 h;
    h.x = u.x * (g.x / (1.f + expf(-g.x)));
    h.y = u.y * (g.y / (1.f + expf(-g.y)));
    h.z = u.z * (g.z / (1.f + expf(-g.z)));
    h.w = u.w * (g.w / (1.f + expf(-g.w)));
    ((float4*)H_)[v] = h;
    int c = (v << 2) % 5504;
    float mm = fmaxf(fmaxf(fabsf(h.x), fabsf(h.y)), fmaxf(fabsf(h.z), fabsf(h.w)));
    if (c < 2752) m0 = fmaxf(m0, mm); else m1 = fmaxf(m1, mm);
  }
  #pragma unroll
  for (int off = 32; off > 0; off >>= 1) {
    m0 = fmaxf(m0, __shfl_xor(m0, off));
    m1 = fmaxf(m1, __shfl_xor(m1, off));
  }
  if ((threadIdx.x & 63) == 0) {
    u32* slots = (u32*)P;
    if (m0 > 0.f) atomicMax(slots + SL_AH, __float_as_uint(m0));
    if (m1 > 0.f) atomicMax(slots + SL_AH + 1, __float_as_uint(m1));
  }
}

// ---- bf16x3 MFMA GEMM (proven 2-phase 128x128) — fallback path only ----
template <int MF, int NF>
__global__ __launch_bounds__(256) void k_gemm(
    const u16* __restrict__ Ah, const u16* __restrict__ Al,
    const u16* __restrict__ Bh, const u16* __restrict__ Bl,
    float* __restrict__ C0, float* __restrict__ C1, int nsplit, int ldc,
    int M, int N, int K) {
  constexpr int BM = MF * 32;
  constexpr int BN = NF * 32;
  constexpr int HALF = (2 * BM + 2 * BN) * 32;
  constexpr int nsegA = BM / 16;
  constexpr int nsegB = BN / 16;
  constexpr int NSEG = 2 * nsegA + 2 * nsegB;
  constexpr int NJ = NSEG / 4;
  static_assert(NJ == 8, "vmcnt immediates assume 8 loads per stage");
  __shared__ __align__(16) u16 S[2 * HALF];

  const int tid = threadIdx.x;
  const int wave = tid >> 6;
  const int lane = tid & 63;

  const int gx = gridDim.x;
  const int nwg = gx * gridDim.y;
  const int orig = blockIdx.y * gx + blockIdx.x;
  const int q = nwg >> 3, r = nwg & 7;
  const int xcd = orig & 7, linb = orig >> 3;
  const int swz = (xcd < r ? xcd * (q + 1) : r * (q + 1) + (xcd - r) * q) + linb;
  const int m0 = (swz % gx) * BM;
  const int n0 = (swz / gx) * BN;

  const int St = K >> 5;
  const int Z = gridDim.z;
  const int zb = St / Z, zr = St - zb * Z;
  const int z = blockIdx.z;
  const int nst = zb + ((z < zr) ? 1 : 0);
  const int k0 = (z * zb + ((z < zr) ? z : zr)) << 5;

  const int wr = wave >> 1, wc = wave & 1;
  const int lrow = lane >> 2;
  const int lcol = (lane & 3) << 3;
  const int fr = lane & 15;
  const int fq4 = (lane >> 4) << 2;
  const int kofs = (lane >> 4) << 3;

  f32x4 acc[MF][NF];
  #pragma unroll
  for (int m = 0; m < MF; ++m)
    #pragma unroll
    for (int n = 0; n < NF; ++n) acc[m][n] = (f32x4){0.f, 0.f, 0.f, 0.f};

  const u16* srcp[NJ];
  int loff[NJ];
  #pragma unroll
  for (int j = 0; j < NJ; ++j) {
    int g = j * 4 + wave;
    const u16* gb; int abase, trow, segi;
    if (g < nsegA)               { gb = Ah; abase = 0;                  trow = m0; segi = g; }
    else if (g < 2 * nsegA)      { gb = Al; abase = BM * 32;            trow = m0; segi = g - nsegA; }
    else if (g < 2 * nsegA + nsegB) { gb = Bh; abase = 2 * BM * 32;     trow = n0; segi = g - 2 * nsegA; }
    else                         { gb = Bl; abase = 2 * BM * 32 + BN * 32; trow = n0; segi = g - 2 * nsegA - nsegB; }
    srcp[j] = gb + (size_t)(trow + segi * 16 + lrow) * K + (k0 + lcol);
    loff[j] = abase + segi * 512;
  }

  int aoh[MF], aol[MF], boh[NF], bol[NF];
  #pragma unroll
  for (int m = 0; m < MF; ++m) {
    int rr = wr * (MF * 16) + m * 16 + fr;
    int idx = rr * 32 + (kofs ^ (((rr >> 1) & 3) << 3));
    aoh[m] = idx;
    aol[m] = BM * 32 + idx;
  }
  #pragma unroll
  for (int n = 0; n < NF; ++n) {
    int rr = wc * (NF * 16) + n * 16 + fr;
    int idx = rr * 32 + (kofs ^ (((rr >> 1) & 3) << 3));
    boh[n] = 2 * BM * 32 + idx;
    bol[n] = 2 * BM * 32 + BN * 32 + idx;
  }

  #define STAGE(bufo)                                           \
    { _Pragma("unroll")                                         \
      for (int j = 0; j < NJ; ++j) {                            \
        gload_lds16(srcp[j], S + (bufo) + loff[j]);             \
        srcp[j] += 32;                                          \
      } }

  #define COMPUTE(bufo)                                                         \
    { short8 afh[MF], afl[MF], bfh[NF], bfl[NF];                                \
      _Pragma("unroll")                                                         \
      for (int m = 0; m < MF; ++m) {                                            \
        afh[m] = *(const short8*)(S + (bufo) + aoh[m]);                         \
        afl[m] = *(const short8*)(S + (bufo) + aol[m]);                         \
      }                                                                         \
      _Pragma("unroll")                                                         \
      for (int n = 0; n < NF; ++n) {                                            \
        bfh[n] = *(const short8*)(S + (bufo) + boh[n]);                         \
        bfl[n] = *(const short8*)(S + (bufo) + bol[n]);                         \
      }                                                                         \
      _Pragma("unroll")                                                         \
      for (int m = 0; m < MF; ++m)                                              \
        _Pragma("unroll")                                                       \
        for (int n = 0; n < NF; ++n) {                                          \
          acc[m][n] = __builtin_amdgcn_mfma_f32_16x16x32_bf16(afh[m], bfh[n], acc[m][n], 0, 0, 0); \
          acc[m][n] = __builtin_amdgcn_mfma_f32_16x16x32_bf16(afh[m], bfl[n], acc[m][n], 0, 0, 0); \
          acc[m][n] = __builtin_amdgcn_mfma_f32_16x16x32_bf16(afl[m], bfh[n], acc[m][n], 0, 0, 0); \
        } }

  int curo = 0;
  STAGE(curo);
  for (int t = 0; t + 1 < nst; ++t) {
    STAGE(curo ^ HALF);
    WAITVM8();
    BARRIER();
    COMPUTE(curo);
    BARRIER();
    curo ^= HALF;
  }
  WAITVM0();
  BARRIER();
  COMPUTE(curo);

  #undef STAGE
  #undef COMPUTE

  float* base = (n0 < nsplit) ? C0 : C1;
  const int ncol0 = (n0 < nsplit) ? 0 : nsplit;
  float* Cz = base + (size_t)z * M * ldc;
  #pragma unroll
  for (int m = 0; m < MF; ++m) {
    #pragma unroll
    for (int n = 0; n < NF; ++n) {
      int row = m0 + wr * (MF * 16) + m * 16 + fq4;
      int col = n0 + wc * (NF * 16) + n * 16 + fr - ncol0;
      float* cp = Cz + (size_t)row * ldc + col;
      f32x4 a = acc[m][n];
      cp[0] = a[0];
      cp[(size_t)ldc] = a[1];
      cp[(size_t)2 * ldc] = a[2];
      cp[(size_t)3 * ldc] = a[3];
    }
  }
}

// ---- 8-phase bf16x3 GEMM, BM=256 x BN=256, 8 waves (2m x 4n, wave=128x64),
//      128KB LDS (1 blk/CU), NJ=8. B fragments hoisted to registers at p0
//      (phase-invariant; 32 VGPRs) — the r11-proven pattern at BN=256.
//      CMODE 0: per-element col split at nsplit (C0 ld=ldc | C1). Z must be 1.
//      CMODE 1: z-split partials, z<4 -> C0+z*M*ldc else C1+(z-4)*M*ldc. ----
template <int CMODE>
__global__ __launch_bounds__(512) void k_gemm8w(
    const u16* __restrict__ Ah, const u16* __restrict__ Al,
    const u16* __restrict__ Bh, const u16* __restrict__ Bl,
    float* __restrict__ C0, float* __restrict__ C1, int nsplit, int ldc,
    int M, int N, int K) {
  constexpr int BM = 256, BN = 256;
  constexpr int HALF = (2 * BM + 2 * BN) * 32;   // 32768 u16 = 64 KB
  constexpr int NJ = 8;
  __shared__ __align__(16) u16 S[2 * HALF];      // 128 KB

  const int tid = threadIdx.x;
  const int wave = tid >> 6;   // 0..7
  const int lane = tid & 63;

  const int gx = gridDim.x;
  const int nwg = gx * gridDim.y;
  const int orig = blockIdx.y * gx + blockIdx.x;
  const int q = nwg >> 3, r = nwg & 7;
  const int xcd = orig & 7, linb = orig >> 3;
  const int swz = (xcd < r ? xcd * (q + 1) : r * (q + 1) + (xcd - r) * q) + linb;
  const int m0 = (swz % gx) * BM;
  const int n0 = (swz / gx) * BN;

  const int St = K >> 5;
  const int Z = gridDim.z;
  const int zb = St / Z, zr = St - zb * Z;
  const int z = blockIdx.z;
  const int nst = zb + ((z < zr) ? 1 : 0);
  const int k0 = (z * zb + ((z < zr) ? z : zr)) << 5;

  const int wr = wave >> 2;    // 0..1 (row half)
  const int wc = wave & 3;     // 0..3 (col quarter, 64 cols each)
  const int lrow = lane >> 2;
  const int lcol = (lane & 3) << 3;
  const int fr = lane & 15;
  const int fq4 = (lane >> 4) << 2;
  const int kofs = (lane >> 4) << 3;
  const int kx = kofs ^ (((fr >> 1) & 3) << 3);  // row-XOR reduces to fr-only

  f32x4 acc[8][4];
  #pragma unroll
  for (int m = 0; m < 8; ++m)
    #pragma unroll
    for (int n = 0; n < 4; ++n) acc[m][n] = (f32x4){0.f, 0.f, 0.f, 0.f};

  // staging: 64 segs (Ah 16, Al 16, Bh 16, Bl 16) over 8 waves -> NJ=8
  const u16* srcp[NJ];
  int loff[NJ];
  #pragma unroll
  for (int j = 0; j < NJ; ++j) {
    int g = j * 8 + wave;
    const u16* gb; int abase, trow, segi;
    if (g < 16)      { gb = Ah; abase = 0;         trow = m0; segi = g; }
    else if (g < 32) { gb = Al; abase = 8192;      trow = m0; segi = g - 16; }
    else if (g < 48) { gb = Bh; abase = 16384;     trow = n0; segi = g - 32; }
    else             { gb = Bl; abase = 24576;     trow = n0; segi = g - 48; }
    srcp[j] = gb + (size_t)(trow + segi * 16 + lrow) * K + (k0 + lcol);
    loff[j] = abase + segi * 512;
  }

  const int aoh0 = (wr * 128 + fr) * 32 + kx;           // + m*512
  const int aol0 = 8192 + aoh0;
  const int boh0 = 16384 + (wc * 64 + fr) * 32 + kx;    // + n*512
  const int bol0 = boh0 + 8192;

  #define ISSUE2(bufo, j0)                                             \
    { gload_lds16(srcp[j0], S + (bufo) + loff[j0]);  srcp[j0] += 32;   \
      gload_lds16(srcp[j0+1], S + (bufo) + loff[j0+1]); srcp[j0+1] += 32; }

  int curo = 0;
  ISSUE2(curo, 0); ISSUE2(curo, 2); ISSUE2(curo, 4); ISSUE2(curo, 6);

  for (int t = 0; t < nst; ++t) {
    const int nxt = curo ^ HALF;
    const bool more = (t + 1 < nst);   // block-uniform
    if (more) { ISSUE2(nxt, 0); WAITVM2(); } else { WAITVM0(); }
    BARRIER();                         // tile t landed for all waves

    short8 bh_[4], bl_[4];             // phase-invariant B fragments (regs)
    #pragma unroll
    for (int p = 0; p < 4; ++p) {
      const int m2 = 2 * p;
      short8 a0h = *(const short8*)(S + curo + aoh0 + m2 * 512);
      short8 a0l = *(const short8*)(S + curo + aol0 + m2 * 512);
      short8 a1h = *(const short8*)(S + curo + aoh0 + (m2 + 1) * 512);
      short8 a1l = *(const short8*)(S + curo + aol0 + (m2 + 1) * 512);
      if (p == 0) {
        #pragma unroll
        for (int n = 0; n < 4; ++n) {
          bh_[n] = *(const short8*)(S + curo + boh0 + n * 512);
          bl_[n] = *(const short8*)(S + curo + bol0 + n * 512);
        }
      }
      if (more) {
        if (p == 0) { ISSUE2(nxt, 2); }
        else if (p == 1) { ISSUE2(nxt, 4); }
        else if (p == 2) { ISSUE2(nxt, 6); }
      }
      BARRIER();
      __builtin_amdgcn_s_setprio(1);
      #pragma unroll
      for (int n = 0; n < 4; ++n) {
        acc[m2][n] = __builtin_amdgcn_mfma_f32_16x16x32_bf16(a0h, bh_[n], acc[m2][n], 0, 0, 0);
        acc[m2][n] = __builtin_amdgcn_mfma_f32_16x16x32_bf16(a0h, bl_[n], acc[m2][n], 0, 0, 0);
        acc[m2][n] = __builtin_amdgcn_mfma_f32_16x16x32_bf16(a0l, bh_[n], acc[m2][n], 0, 0, 0);
        acc[m2+1][n] = __builtin_amdgcn_mfma_f32_16x16x32_bf16(a1h, bh_[n], acc[m2+1][n], 0, 0, 0);
        acc[m2+1][n] = __builtin_amdgcn_mfma_f32_16x16x32_bf16(a1h, bl_[n], acc[m2+1][n], 0, 0, 0);
        acc[m2+1][n] = __builtin_amdgcn_mfma_f32_16x16x32_bf16(a1l, bh_[n], acc[m2+1][n], 0, 0, 0);
      }
      __builtin_amdgcn_s_setprio(0);
      BARRIER();
    }
    curo ^= HALF;
  }
  #undef ISSUE2

  if (CMODE == 0) {
    // per-element column split (UP | GATE seam may cross a 256-wide tile)
    #pragma unroll
    for (int m = 0; m < 8; ++m) {
      #pragma unroll
      for (int n = 0; n < 4; ++n) {
        int row = m0 + wr * 128 + m * 16 + fq4;
        int col = n0 + wc * 64 + n * 16 + fr;
        float* base = (col < nsplit) ? C0 : C1;
        int cw = (col < nsplit) ? col : col - nsplit;
        float* cp = base + (size_t)row * ldc + cw;
        f32x4 a = acc[m][n];
        cp[0] = a[0];
        cp[(size_t)ldc] = a[1];
        cp[(size_t)2 * ldc] = a[2];
        cp[(size_t)3 * ldc] = a[3];
      }
    }
  } else {
    float* Cz = (z < 4) ? (C0 + (size_t)z * M * ldc) : (C1 + (size_t)(z - 4) * M * ldc);
    #pragma unroll
    for (int m = 0; m < 8; ++m) {
      #pragma unroll
      for (int n = 0; n < 4; ++n) {
        int row = m0 + wr * 128 + m * 16 + fq4;
        int col = n0 + wc * 64 + n * 16 + fr;
        float* cp = Cz + (size_t)row * ldc + col;
        f32x4 a = acc[m][n];
        cp[0] = a[0];
        cp[(size_t)ldc] = a[1];
        cp[(size_t)2 * ldc] = a[2];
        cp[(size_t)3 * ldc] = a[3];
      }
    }
  }
}

// ---- out = sum of 8 partials (4 at p0, 4 at p1), fixed order ----
__global__ __launch_bounds__(256) void k_reduce8(const float4* __restrict__ p0,
                                                 const float4* __restrict__ p1,
                                                 float4* __restrict__ out, int nvec) {
  int stride = gridDim.x * blockDim.x;
  for (int i = blockIdx.x * blockDim.x + threadIdx.x; i < nvec; i += stride) {
    float4 s = p0[i];
    #pragma unroll
    for (int zz = 1; zz < 4; ++zz) {
      float4 b = p0[(size_t)zz * nvec + i];
      s.x += b.x; s.y += b.y; s.z += b.z; s.w += b.w;
    }
    #pragma unroll
    for (int zz = 0; zz < 4; ++zz) {
      float4 b = p1[(size_t)zz * nvec + i];
      s.x += b.x; s.y += b.y; s.z += b.z; s.w += b.w;
    }
    out[i] = s;
  }
}

// ---- out = p0+p1+p2+p3 (fallback reduce) ----
__global__ __launch_bounds__(256) void k_reduce4(const float4* __restrict__ p,
                                                 float4* __restrict__ out, int nvec) {
  int stride = gridDim.x * blockDim.x;
  for (int i = blockIdx.x * blockDim.x + threadIdx.x; i < nvec; i += stride) {
    float4 a = p[i], b = p[nvec + i], c = p[2 * nvec + i], d = p[3 * nvec + i];
    float4 o;
    o.x = ((a.x + b.x) + c.x) + d.x;
    o.y = ((a.y + b.y) + c.y) + d.y;
    o.z = ((a.z + b.z) + c.z) + d.z;
    o.w = ((a.w + b.w) + c.w) + d.w;
    out[i] = o;
  }
}

extern "C" void kernel_launch(void* const* d_in, const int* in_sizes, int n_in,
                              void* d_out, int out_size, void* d_ws, size_t ws_size,
                              hipStream_t stream) {
  const float* x  = (const float*)d_in[0];
  const float* ph = (const float*)d_in[1];
  const float* pi = (const float*)d_in[2];
  const float* pa = (const float*)d_in[3];
  const float* pw = (const float*)d_in[4];
  const float* Wg = (const float*)d_in[5];
  const float* Wu = (const float*)d_in[6];
  const float* Wd = (const float*)d_in[7];
  float* out = (float*)d_out;

  const u32 magic5504 = (u32)(((1ULL << 40) + 5503ULL) / 5504ULL);
  char* ws = (char*)d_ws;

  const size_t szX1 = (size_t)1024 * 3072 * 2;          // 6.29 MB each
  const size_t szWug = (size_t)11008 * 3072 * 2;        // 67.63 MB each (h, l)
  const size_t szUP = (size_t)1024 * 5504 * 4;          // 22.54 MB each
  const size_t fused_need = 1024 + 2 * szX1 + 2 * szWug + 2 * szUP;   // ~193 MB

  if (ws_size >= fused_need) {
    // ---------------- fused up+gate path, both GEMMs on k_gemm8w ----------------
    size_t off = 0;
    float* P = (float*)(ws + off); off += 1024;
    u16* X1h = (u16*)(ws + off); off += szX1;
    u16* X1l = (u16*)(ws + off); off += szX1;
    u16* Wh  = (u16*)(ws + off); off += szWug;   // rows 0..5503 Wu, 5504..11007 Wg
    u16* Wl  = (u16*)(ws + off); off += szWug;
    float* UP   = (float*)(ws + off); off += szUP;
    float* GATE = (float*)(ws + off); off += szUP;
    float* H = UP;   // h overwrites up in place
    // phase-2 aliases (upgate weights dead after fused GEMM):
    u16* X2h = Wh;
    u16* X2l = Wh + (size_t)1024 * 8256;
    float* DPz1 = (float*)(Wh + (size_t)2 * 1024 * 8256);  // 33.55 <= 33.81 MB tail
    float* DPz0 = UP;                                      // UP+GATE: 33.55 <= 45.1 MB
    u16* Wdh = Wl;
    u16* Wdl = Wl + (size_t)2048 * 8256;

    k_init<<<1, 64, 0, stream>>>(ph, pi, pa, pw, P);
    k_absmax4<<<1792, 256, 0, stream>>>(x, Wu, Wg, Wd, magic5504, P);
    k_params1<<<1, 64, 0, stream>>>(P);

    k_build1<<<1536 + 16512, 256, 0, stream>>>(x, Wu, Wg, P, X1h, X1l, Wh, Wl);

    // upgate: 8-phase 256x256, grid 4x43 = 172 blocks (single fill), z=1
    // full-K per output -> bit-exact; per-element col split at 5504
    dim3 g1(1024 / 256, 11008 / 256, 1);
    k_gemm8w<0><<<g1, 512, 0, stream>>>(X1h, X1l, Wh, Wl, UP, GATE, 5504, 5504,
                                        1024, 11008, 3072);

    k_h<<<2048, 256, 0, stream>>>(UP, GATE, H, P);
    k_params2<<<1, 64, 0, stream>>>(P);

    k_build2<<<4128 + 8256, 256, 0, stream>>>(H, Wd, P, X2h, X2l, Wdh, Wdl);

    // down: 8-phase 256x256, split-K z=8 -> 4*8*8 = 256 blocks = exactly 1/CU
    dim3 g2(1024 / 256, 2048 / 256, 8);
    k_gemm8w<1><<<g2, 512, 0, stream>>>(X2h, X2l, Wdh, Wdl, DPz0, DPz1, 2048, 2048,
                                        1024, 2048, 8256);
    k_reduce8<<<2048, 256, 0, stream>>>((const float4*)DPz0, (const float4*)DPz1,
                                        (float4*)out, (1024 * 2048) / 4);
    return;
  }

  // ---------------- fallback: round-6 exact layout, proven kernels ----------------
  size_t off = 0;
  float* P = (float*)(ws + off); off += 1024;
  u16* X1h = (u16*)(ws + off); off += szX1;
  u16* X1l = (u16*)(ws + off); off += szX1;
  u16* Wh  = (u16*)(ws + off); off += (size_t)5504 * 3072 * 2;
  u16* Wl  = (u16*)(ws + off); off += (size_t)5504 * 3072 * 2;
  float* UP   = (float*)(ws + off); off += (size_t)1024 * 5504 * 4;
  float* GATE = (float*)(ws + off); off += (size_t)1024 * 5504 * 4;
  u16* X2h = (u16*)(ws + off); off += (size_t)1024 * 8256 * 2;
  u16* X2l = (u16*)(ws + off); off += (size_t)1024 * 8256 * 2;
  float* H = UP;
  float* DPART = UP;
  if (ws_size < off) return;

  k_init<<<1, 64, 0, stream>>>(ph, pi, pa, pw, P);
  k_absmax4<<<1792, 256, 0, stream>>>(x, Wu, Wg, Wd, magic5504, P);
  k_params1<<<1, 64, 0, stream>>>(P);

  {
    int nch = 1024 * (3072 / 8);
    k_build_x<<<(nch + 255) / 256, 256, 0, stream>>>(x, P, X1h, X1l, 1024, 2048, 1024, 3072, P_SX);
  }
  {
    int nch = 5504 * (3072 / 8);
    k_build_w<<<(nch + 255) / 256, 256, 0, stream>>>(Wu, P, Wh, Wl, 5504, 2048, 1024, 3072, P_SWUP, 2752);
  }
  dim3 g1(1024 / 128, 5504 / 128, 1);
  k_gemm<4, 4><<<g1, 256, 0, stream>>>(X1h, X1l, Wh, Wl, UP, UP, 5504, 5504, 1024, 5504, 3072);
  {
    int nch = 5504 * (3072 / 8);
    k_build_w<<<(nch + 255) / 256, 256, 0, stream>>>(Wg, P, Wh, Wl, 5504, 2048, 1024, 3072, P_SWGATE, 2752);
  }
  k_gemm<4, 4><<<g1, 256, 0, stream>>>(X1h, X1l, Wh, Wl, GATE, GATE, 5504, 5504, 1024, 5504, 3072);

  k_h<<<2048, 256, 0, stream>>>(UP, GATE, H, P);
  k_params2<<<1, 64, 0, stream>>>(P);

  {
    int nch = 1024 * (8256 / 8);
    k_build_x<<<(nch + 255) / 256, 256, 0, stream>>>(H, P, X2h, X2l, 1024, 5504, 2752, 8256, P_SH);
  }
  {
    int nch = 2048 * (8256 / 8);
    k_build_w<<<(nch + 255) / 256, 256, 0, stream>>>(Wd, P, Wh, Wl, 2048, 5504, 2752, 8256, P_SWDOWN, 1024);
  }
  dim3 g2(1024 / 128, 2048 / 128, 4);
  k_gemm<4, 4><<<g2, 256, 0, stream>>>(X2h, X2l, Wh, Wl, DPART, DPART, 2048, 2048, 1024, 2048, 8256);
  k_reduce4<<<2048, 256, 0, stream>>>((const float4*)DPART, (float4*)out, (1024 * 2048) / 4);
}

// Round 15
// 472.588 us; speedup vs baseline: 1.3171x; 1.2191x over previous
//
#include <hip/hip_runtime.h>

typedef __attribute__((ext_vector_type(8))) short short8;
typedef __attribute__((ext_vector_type(4))) float f32x4;
typedef unsigned short u16;
typedef unsigned int u32;
typedef unsigned long long u64;

// params layout (floats)
#define P_WH 0
#define P_WI 2
#define P_WA 4
#define P_WW 6
#define SL_AX 8
#define SL_WUP 12
#define SL_WGATE 16
#define SL_WDOWN 20
#define SL_AH 24
#define P_SX 28
#define P_SWUP 32
#define P_SWGATE 40
#define P_SWDOWN 48
#define P_SH 56

__device__ __forceinline__ u16 f2bf(float f) {
  u32 u = __float_as_uint(f);
  u = (u + 0x7FFFu + ((u >> 16) & 1u)) >> 16;
  return (u16)u;
}
__device__ __forceinline__ float bf2f(u16 h) { return __uint_as_float(((u32)h) << 16); }
__device__ __forceinline__ float fquant(float v, float s) { return rintf(v / s) * s; }

typedef const __attribute__((address_space(1))) u32 gl_u32;
typedef __attribute__((address_space(3))) u32 lds_u32;
__device__ __forceinline__ void gload_lds16(const void* g, void* l) {
  __builtin_amdgcn_global_load_lds((gl_u32*)g, (lds_u32*)l, 16, 0, 0);
}

#define WAITVM8()  asm volatile("s_waitcnt vmcnt(8)" ::: "memory")
#define WAITVM2()  asm volatile("s_waitcnt vmcnt(2)" ::: "memory")
#define WAITVM0()  asm volatile("s_waitcnt vmcnt(0)" ::: "memory")
#define BARRIER()  asm volatile("s_barrier" ::: "memory")

// ---- init: zero absmax slots, compute the four 2-way softmaxes ----
__global__ void k_init(const float* ph, const float* pi, const float* pa,
                       const float* pw, float* P) {
  if (threadIdx.x == 0) {
    u32* U = (u32*)P;
    for (int i = SL_AX; i < SL_AH + 2; ++i) U[i] = 0u;
    const float* src[4] = {ph, pi, pa, pw};
    #pragma unroll
    for (int t = 0; t < 4; ++t) {
      float a = src[t][0], b = src[t][1];
      float mx = fmaxf(a, b);
      float ea = expf(a - mx), eb = expf(b - mx);
      float s = ea + eb;
      P[t * 2 + 0] = ea / s;
      P[t * 2 + 1] = eb / s;
    }
  }
}

// ---- quadrant absmax: branchless, ILP-4, pow2 fast path, block-reduced ----
template <bool POW2>
__device__ __forceinline__ void amax_proc(float4 d, int v, u32 magic, int C,
                                          int r0, int c0,
                                          float& m0, float& m1, float& m2, float& m3) {
  int lin = v << 2;
  int o, c;
  if (POW2) { o = lin >> 11; c = lin & 2047; }
  else {
    o = (int)(((u64)(u32)lin * magic) >> 40);
    c = lin - o * C;
  }
  float mm = fmaxf(fmaxf(fabsf(d.x), fabsf(d.y)), fmaxf(fabsf(d.z), fabsf(d.w)));
  bool rlo = o < r0, clo = c < c0;
  m0 = fmaxf(m0, (rlo && clo) ? mm : 0.f);
  m1 = fmaxf(m1, (rlo && !clo) ? mm : 0.f);
  m2 = fmaxf(m2, (!rlo && clo) ? mm : 0.f);
  m3 = fmaxf(m3, (!rlo && !clo) ? mm : 0.f);
}

template <bool POW2>
__device__ __forceinline__ void absmax_dev(const float4* __restrict__ A4,
                                           int nvec, u32 magic, int C, int r0, int c0,
                                           int slotbase, float* P, int bid, int nb) {
  float m0 = 0.f, m1 = 0.f, m2 = 0.f, m3 = 0.f;
  const int tid = threadIdx.x;
  const int step = nb * 256;
  int v = bid * 256 + tid;
  for (; v + 3 * step < nvec; v += 4 * step) {
    float4 d0 = A4[v];
    float4 d1 = A4[v + step];
    float4 d2 = A4[v + 2 * step];
    float4 d3 = A4[v + 3 * step];
    amax_proc<POW2>(d0, v,            magic, C, r0, c0, m0, m1, m2, m3);
    amax_proc<POW2>(d1, v + step,     magic, C, r0, c0, m0, m1, m2, m3);
    amax_proc<POW2>(d2, v + 2 * step, magic, C, r0, c0, m0, m1, m2, m3);
    amax_proc<POW2>(d3, v + 3 * step, magic, C, r0, c0, m0, m1, m2, m3);
  }
  for (; v < nvec; v += step) {
    float4 d0 = A4[v];
    amax_proc<POW2>(d0, v, magic, C, r0, c0, m0, m1, m2, m3);
  }
  #pragma unroll
  for (int off = 32; off > 0; off >>= 1) {
    m0 = fmaxf(m0, __shfl_xor(m0, off));
    m1 = fmaxf(m1, __shfl_xor(m1, off));
    m2 = fmaxf(m2, __shfl_xor(m2, off));
    m3 = fmaxf(m3, __shfl_xor(m3, off));
  }
  __shared__ float red[16];
  const int wave = tid >> 6;
  if ((tid & 63) == 0) {
    red[wave * 4 + 0] = m0;
    red[wave * 4 + 1] = m1;
    red[wave * 4 + 2] = m2;
    red[wave * 4 + 3] = m3;
  }
  __syncthreads();
  if (tid < 4) {
    float mm = fmaxf(fmaxf(red[tid], red[4 + tid]), fmaxf(red[8 + tid], red[12 + tid]));
    if (mm > 0.f) atomicMax((u32*)P + slotbase + tid, __float_as_uint(mm));
  }
}

__global__ __launch_bounds__(256) void k_absmax4(const float* x, const float* Wu,
                                                 const float* Wg, const float* Wd,
                                                 u32 magic5504, float* P) {
  int b = blockIdx.x;
  if (b < 256)        absmax_dev<true >((const float4*)x,  (1024 * 2048) >> 2, 0, 2048, 1024, 1024, SL_AX,    P, b,        256);
  else if (b < 768)   absmax_dev<true >((const float4*)Wu, (5504 * 2048) >> 2, 0, 2048, 2752, 1024, SL_WUP,   P, b - 256,  512);
  else if (b < 1280)  absmax_dev<true >((const float4*)Wg, (5504 * 2048) >> 2, 0, 2048, 2752, 1024, SL_WGATE, P, b - 768,  512);
  else                absmax_dev<false>((const float4*)Wd, (2048 * 5504) >> 2, magic5504, 5504, 1024, 2752, SL_WDOWN, P, b - 1280, 512);
}

// ---- scales ----
__global__ void k_params1(float* P) {
  if (threadIdx.x != 0 || blockIdx.x != 0) return;
  u32* U = (u32*)P;
  float x00 = __uint_as_float(U[SL_AX + 0]);
  float x01 = __uint_as_float(U[SL_AX + 1]);
  float ax0 = x00;
  float ax1 = fmaxf(x00, x01);
  P[P_SX + 0] = fmaxf(ax0 / 7.f, 1e-8f);
  P[P_SX + 1] = fmaxf(ax0 / 127.f, 1e-8f);
  P[P_SX + 2] = fmaxf(ax1 / 7.f, 1e-8f);
  P[P_SX + 3] = fmaxf(ax1 / 127.f, 1e-8f);
  const int sl[3] = {SL_WUP, SL_WGATE, SL_WDOWN};
  const int sb[3] = {P_SWUP, P_SWGATE, P_SWDOWN};
  #pragma unroll
  for (int t = 0; t < 3; ++t) {
    float q00 = __uint_as_float(U[sl[t] + 0]);
    float q01 = __uint_as_float(U[sl[t] + 1]);
    float q10 = __uint_as_float(U[sl[t] + 2]);
    float q11 = __uint_as_float(U[sl[t] + 3]);
    float a0 = q00;
    float a1 = fmaxf(q00, q10);
    float a2 = fmaxf(q00, q01);
    float a3 = fmaxf(fmaxf(q00, q01), fmaxf(q10, q11));
    float aa[4] = {a0, a1, a2, a3};
    #pragma unroll
    for (int ij = 0; ij < 4; ++ij) {
      P[sb[t] + ij * 2 + 0] = fmaxf(aa[ij] / 7.f, 1e-8f);
      P[sb[t] + ij * 2 + 1] = fmaxf(aa[ij] / 127.f, 1e-8f);
    }
  }
}

__global__ void k_params2(float* P) {
  if (threadIdx.x != 0 || blockIdx.x != 0) return;
  u32* U = (u32*)P;
  float a0 = __uint_as_float(U[SL_AH]);
  float a1 = fmaxf(a0, __uint_as_float(U[SL_AH + 1]));
  P[P_SH + 0] = fmaxf(a0 / 7.f, 1e-8f);
  P[P_SH + 1] = fmaxf(a0 / 127.f, 1e-8f);
  P[P_SH + 2] = fmaxf(a1 / 7.f, 1e-8f);
  P[P_SH + 3] = fmaxf(a1 / 127.f, 1e-8f);
}

// ---- build activation operand element (chunk-XOR pre-swizzled) ----
__device__ __forceinline__ void build_x_one(
    const float* __restrict__ src, const float* __restrict__ P,
    u16* __restrict__ Xh, u16* __restrict__ Xl,
    int Csrc, int cin0, int K, int sbx, int gid, int kpr) {
  int row = gid / kpr;
  int kc_out = (gid - row * kpr) << 3;
  int kc_log = kc_out ^ (((row >> 1) & 3) << 3);
  int i = (kc_log >= cin0) ? 1 : 0;
  int c = kc_log - i * cin0;
  float pin = P[P_WH + i];
  float wa0 = P[P_WA], wa1 = P[P_WA + 1];
  float s4 = P[sbx + i * 2], s8 = P[sbx + i * 2 + 1];
  const float* sp = src + (size_t)row * Csrc + c;
  float v[8];
  *(float4*)&v[0] = *(const float4*)sp;
  *(float4*)&v[4] = *(const float4*)(sp + 4);
  short8 hv, lv;
  #pragma unroll
  for (int e = 0; e < 8; ++e) {
    float val = pin * (wa0 * fquant(v[e], s4) + wa1 * fquant(v[e], s8));
    u16 h = f2bf(val);
    hv[e] = (short)h;
    lv[e] = (short)f2bf(val - bf2f(h));
  }
  size_t off = (size_t)row * K + kc_out;
  *(short8*)(Xh + off) = hv;
  *(short8*)(Xl + off) = lv;
}

// ---- build weight operand element; row_src = source row (scale select),
//      row_store = operand row (XOR key + store position) ----
__device__ __forceinline__ void build_w_one(
    const float* __restrict__ W, const float* __restrict__ P,
    u16* __restrict__ Wh, u16* __restrict__ Wl,
    int Csrc, int cin0, int K, int sbw, int cout0,
    int row_src, int row_store, int kc_out) {
  int kc_log = kc_out ^ (((row_store >> 1) & 3) << 3);
  int i = (kc_log >= cin0) ? 1 : 0;
  int c = kc_log - i * cin0;
  float wi0 = P[P_WI], wi1 = P[P_WI + 1];
  float ww0 = P[P_WW], ww1 = P[P_WW + 1];
  float s00 = P[sbw + i * 4 + 0];
  float s01 = P[sbw + i * 4 + 1];
  float s10 = P[sbw + i * 4 + 2];
  float s11 = P[sbw + i * 4 + 3];
  float keep0 = (row_src < cout0) ? wi0 : 0.f;
  const float* sp = W + (size_t)row_src * Csrc + c;
  float v[8];
  *(float4*)&v[0] = *(const float4*)sp;
  *(float4*)&v[4] = *(const float4*)(sp + 4);
  short8 hv, lv;
  #pragma unroll
  for (int e = 0; e < 8; ++e) {
    float w = v[e];
    float t0 = ww0 * fquant(w, s00) + ww1 * fquant(w, s01);
    float t1 = ww0 * fquant(w, s10) + ww1 * fquant(w, s11);
    float val = keep0 * t0 + wi1 * t1;
    u16 h = f2bf(val);
    hv[e] = (short)h;
    lv[e] = (short)f2bf(val - bf2f(h));
  }
  size_t off = (size_t)row_store * K + kc_out;
  *(short8*)(Wh + off) = hv;
  *(short8*)(Wl + off) = lv;
}

// standalone builders (fallback path)
__global__ __launch_bounds__(256) void k_build_x(
    const float* __restrict__ src, const float* __restrict__ P,
    u16* __restrict__ Xh, u16* __restrict__ Xl,
    int rows, int Csrc, int cin0, int K, int sbx) {
  int kpr = K >> 3;
  int nch = rows * kpr;
  int gid = blockIdx.x * blockDim.x + threadIdx.x;
  if (gid >= nch) return;
  build_x_one(src, P, Xh, Xl, Csrc, cin0, K, sbx, gid, kpr);
}

__global__ __launch_bounds__(256) void k_build_w(
    const float* __restrict__ W, const float* __restrict__ P,
    u16* __restrict__ Wh, u16* __restrict__ Wl,
    int R, int Csrc, int cin0, int K, int sbw, int cout0) {
  int kpr = K >> 3;
  int nch = R * kpr;
  int gid = blockIdx.x * blockDim.x + threadIdx.x;
  if (gid >= nch) return;
  int row = gid / kpr;
  int kc_out = (gid - row * kpr) << 3;
  build_w_one(W, P, Wh, Wl, Csrc, cin0, K, sbw, cout0, row, row, kc_out);
}

// merged phase-1 build: x (1536 blocks) + interleaved Wu/Wg (16512 blocks).
// 16-col interleave: Wu row u -> operand row 2*(u>>4)*16 + (u&15);
//                    Wg row g -> same + 16. (low 4 bits preserved -> XOR key same)
__global__ __launch_bounds__(256) void k_build1(
    const float* __restrict__ x, const float* __restrict__ Wu,
    const float* __restrict__ Wg, const float* __restrict__ P,
    u16* __restrict__ X1h, u16* __restrict__ X1l,
    u16* __restrict__ Wh, u16* __restrict__ Wl) {
  int bid = blockIdx.x;
  if (bid < 1536) {
    int gid = bid * 256 + threadIdx.x;
    build_x_one(x, P, X1h, X1l, 2048, 1024, 3072, P_SX, gid, 384);
  } else {
    int gid = (bid - 1536) * 256 + threadIdx.x;
    const int nch = 5504 * 384;
    bool isg = gid >= nch;
    int g2 = isg ? gid - nch : gid;
    int row = g2 / 384;
    int kc_out = (g2 - row * 384) << 3;
    int row_store = (((row >> 4) << 5) + (row & 15)) + (isg ? 16 : 0);
    if (!isg)
      build_w_one(Wu, P, Wh, Wl, 2048, 1024, 3072, P_SWUP,   2752, row, row_store, kc_out);
    else
      build_w_one(Wg, P, Wh, Wl, 2048, 1024, 3072, P_SWGATE, 2752, row, row_store, kc_out);
  }
}

// merged phase-2 build: x2 (4128 blocks) + Wd (8256 blocks)
__global__ __launch_bounds__(256) void k_build2(
    const float* __restrict__ H, const float* __restrict__ Wd,
    const float* __restrict__ P,
    u16* __restrict__ X2h, u16* __restrict__ X2l,
    u16* __restrict__ Wdh, u16* __restrict__ Wdl) {
  int bid = blockIdx.x;
  if (bid < 4128) {
    int gid = bid * 256 + threadIdx.x;
    build_x_one(H, P, X2h, X2l, 5504, 2752, 8256, P_SH, gid, 1032);
  } else {
    int gid = (bid - 4128) * 256 + threadIdx.x;
    int row = gid / 1032;
    int kc_out = (gid - row * 1032) << 3;
    build_w_one(Wd, P, Wdh, Wdl, 5504, 2752, 8256, P_SWDOWN, 1024, row, row, kc_out);
  }
}

// ---- h = silu(gate)*up, fused h-absmax (fallback path only) ----
__global__ __launch_bounds__(256) void k_h(const float* __restrict__ U_,
                                           const float* __restrict__ G_,
                                           float* __restrict__ H_, float* P) {
  int nvec = (1024 * 5504) >> 2;
  int gstride = gridDim.x * blockDim.x;
  float m0 = 0.f, m1 = 0.f;
  for (int v = blockIdx.x * blockDim.x + threadIdx.x; v < nvec; v += gstride) {
    float4 u = ((const float4*)U_)[v];
    float4 g = ((const float4*)G_)[v];
    float4 h;
    h.x = u.x * (g.x / (1.f + expf(-g.x)));
    h.y = u.y * (g.y / (1.f + expf(-g.y)));
    h.z = u.z * (g.z / (1.f + expf(-g.z)));
    h.w = u.w * (g.w / (1.f + expf(-g.w)));
    ((float4*)H_)[v] = h;
    int c = (v << 2) % 5504;
    float mm = fmaxf(fmaxf(fabsf(h.x), fabsf(h.y)), fmaxf(fabsf(h.z), fabsf(h.w)));
    if (c < 2752) m0 = fmaxf(m0, mm); else m1 = fmaxf(m1, mm);
  }
  #pragma unroll
  for (int off = 32; off > 0; off >>= 1) {
    m0 = fmaxf(m0, __shfl_xor(m0, off));
    m1 = fmaxf(m1, __shfl_xor(m1, off));
  }
  if ((threadIdx.x & 63) == 0) {
    u32* slots = (u32*)P;
    if (m0 > 0.f) atomicMax(slots + SL_AH, __float_as_uint(m0));
    if (m1 > 0.f) atomicMax(slots + SL_AH + 1, __float_as_uint(m1));
  }
}

// ---- bf16x3 MFMA GEMM (proven 2-phase 128x128) — fallback path only ----
template <int MF, int NF>
__global__ __launch_bounds__(256) void k_gemm(
    const u16* __restrict__ Ah, const u16* __restrict__ Al,
    const u16* __restrict__ Bh, const u16* __restrict__ Bl,
    float* __restrict__ C0, float* __restrict__ C1, int nsplit, int ldc,
    int M, int N, int K) {
  constexpr int BM = MF * 32;
  constexpr int BN = NF * 32;
  constexpr int HALF = (2 * BM + 2 * BN) * 32;
  constexpr int nsegA = BM / 16;
  constexpr int nsegB = BN / 16;
  constexpr int NSEG = 2 * nsegA + 2 * nsegB;
  constexpr int NJ = NSEG / 4;
  static_assert(NJ == 8, "vmcnt immediates assume 8 loads per stage");
  __shared__ __align__(16) u16 S[2 * HALF];

  const int tid = threadIdx.x;
  const int wave = tid >> 6;
  const int lane = tid & 63;

  const int gx = gridDim.x;
  const int nwg = gx * gridDim.y;
  const int orig = blockIdx.y * gx + blockIdx.x;
  const int q = nwg >> 3, r = nwg & 7;
  const int xcd = orig & 7, linb = orig >> 3;
  const int swz = (xcd < r ? xcd * (q + 1) : r * (q + 1) + (xcd - r) * q) + linb;
  const int m0 = (swz % gx) * BM;
  const int n0 = (swz / gx) * BN;

  const int St = K >> 5;
  const int Z = gridDim.z;
  const int zb = St / Z, zr = St - zb * Z;
  const int z = blockIdx.z;
  const int nst = zb + ((z < zr) ? 1 : 0);
  const int k0 = (z * zb + ((z < zr) ? z : zr)) << 5;

  const int wr = wave >> 1, wc = wave & 1;
  const int lrow = lane >> 2;
  const int lcol = (lane & 3) << 3;
  const int fr = lane & 15;
  const int fq4 = (lane >> 4) << 2;
  const int kofs = (lane >> 4) << 3;

  f32x4 acc[MF][NF];
  #pragma unroll
  for (int m = 0; m < MF; ++m)
    #pragma unroll
    for (int n = 0; n < NF; ++n) acc[m][n] = (f32x4){0.f, 0.f, 0.f, 0.f};

  const u16* srcp[NJ];
  int loff[NJ];
  #pragma unroll
  for (int j = 0; j < NJ; ++j) {
    int g = j * 4 + wave;
    const u16* gb; int abase, trow, segi;
    if (g < nsegA)               { gb = Ah; abase = 0;                  trow = m0; segi = g; }
    else if (g < 2 * nsegA)      { gb = Al; abase = BM * 32;            trow = m0; segi = g - nsegA; }
    else if (g < 2 * nsegA + nsegB) { gb = Bh; abase = 2 * BM * 32;     trow = n0; segi = g - 2 * nsegA; }
    else                         { gb = Bl; abase = 2 * BM * 32 + BN * 32; trow = n0; segi = g - 2 * nsegA - nsegB; }
    srcp[j] = gb + (size_t)(trow + segi * 16 + lrow) * K + (k0 + lcol);
    loff[j] = abase + segi * 512;
  }

  int aoh[MF], aol[MF], boh[NF], bol[NF];
  #pragma unroll
  for (int m = 0; m < MF; ++m) {
    int rr = wr * (MF * 16) + m * 16 + fr;
    int idx = rr * 32 + (kofs ^ (((rr >> 1) & 3) << 3));
    aoh[m] = idx;
    aol[m] = BM * 32 + idx;
  }
  #pragma unroll
  for (int n = 0; n < NF; ++n) {
    int rr = wc * (NF * 16) + n * 16 + fr;
    int idx = rr * 32 + (kofs ^ (((rr >> 1) & 3) << 3));
    boh[n] = 2 * BM * 32 + idx;
    bol[n] = 2 * BM * 32 + BN * 32 + idx;
  }

  #define STAGE(bufo)                                           \
    { _Pragma("unroll")                                         \
      for (int j = 0; j < NJ; ++j) {                            \
        gload_lds16(srcp[j], S + (bufo) + loff[j]);             \
        srcp[j] += 32;                                          \
      } }

  #define COMPUTE(bufo)                                                         \
    { short8 afh[MF], afl[MF], bfh[NF], bfl[NF];                                \
      _Pragma("unroll")                                                         \
      for (int m = 0; m < MF; ++m) {                                            \
        afh[m] = *(const short8*)(S + (bufo) + aoh[m]);                         \
        afl[m] = *(const short8*)(S + (bufo) + aol[m]);                         \
      }                                                                         \
      _Pragma("unroll")                                                         \
      for (int n = 0; n < NF; ++n) {                                            \
        bfh[n] = *(const short8*)(S + (bufo) + boh[n]);                         \
        bfl[n] = *(const short8*)(S + (bufo) + bol[n]);                         \
      }                                                                         \
      _Pragma("unroll")                                                         \
      for (int m = 0; m < MF; ++m)                                              \
        _Pragma("unroll")                                                       \
        for (int n = 0; n < NF; ++n) {                                          \
          acc[m][n] = __builtin_amdgcn_mfma_f32_16x16x32_bf16(afh[m], bfh[n], acc[m][n], 0, 0, 0); \
          acc[m][n] = __builtin_amdgcn_mfma_f32_16x16x32_bf16(afh[m], bfl[n], acc[m][n], 0, 0, 0); \
          acc[m][n] = __builtin_amdgcn_mfma_f32_16x16x32_bf16(afl[m], bfh[n], acc[m][n], 0, 0, 0); \
        } }

  int curo = 0;
  STAGE(curo);
  for (int t = 0; t + 1 < nst; ++t) {
    STAGE(curo ^ HALF);
    WAITVM8();
    BARRIER();
    COMPUTE(curo);
    BARRIER();
    curo ^= HALF;
  }
  WAITVM0();
  BARRIER();
  COMPUTE(curo);

  #undef STAGE
  #undef COMPUTE

  float* base = (n0 < nsplit) ? C0 : C1;
  const int ncol0 = (n0 < nsplit) ? 0 : nsplit;
  float* Cz = base + (size_t)z * M * ldc;
  #pragma unroll
  for (int m = 0; m < MF; ++m) {
    #pragma unroll
    for (int n = 0; n < NF; ++n) {
      int row = m0 + wr * (MF * 16) + m * 16 + fq4;
      int col = n0 + wc * (NF * 16) + n * 16 + fr - ncol0;
      float* cp = Cz + (size_t)row * ldc + col;
      f32x4 a = acc[m][n];
      cp[0] = a[0];
      cp[(size_t)ldc] = a[1];
      cp[(size_t)2 * ldc] = a[2];
      cp[(size_t)3 * ldc] = a[3];
    }
  }
}

// ---- 8-phase bf16x3 GEMM, BM=256 x BN=256, 8 waves, 128KB LDS (1 blk/CU),
//      NJ=8, B fragments hoisted at p0 (proven r14).
//      CMODE 1: z-split partials, z<4 -> C0+z*M*ldc else C1+(z-4)*M*ldc.
//      CMODE 2: fused h-epilogue (interleaved up|gate 16-col pairs):
//        acc[m][n] (n even) = up, acc[m][n+1] = gate for SAME logical cols;
//        h = up*silu(gate) written to C0 ([1024][5504], ldc), h-absmax
//        atomicMax'd into P (C1 = P). Z must be 1. ----
template <int CMODE>
__global__ __launch_bounds__(512) void k_gemm8w(
    const u16* __restrict__ Ah, const u16* __restrict__ Al,
    const u16* __restrict__ Bh, const u16* __restrict__ Bl,
    float* __restrict__ C0, float* __restrict__ C1, int nsplit, int ldc,
    int M, int N, int K) {
  constexpr int BM = 256, BN = 256;
  constexpr int HALF = (2 * BM + 2 * BN) * 32;   // 32768 u16 = 64 KB
  constexpr int NJ = 8;
  __shared__ __align__(16) u16 S[2 * HALF];      // 128 KB

  const int tid = threadIdx.x;
  const int wave = tid >> 6;   // 0..7
  const int lane = tid & 63;

  const int gx = gridDim.x;
  const int nwg = gx * gridDim.y;
  const int orig = blockIdx.y * gx + blockIdx.x;
  const int q = nwg >> 3, r = nwg & 7;
  const int xcd = orig & 7, linb = orig >> 3;
  const int swz = (xcd < r ? xcd * (q + 1) : r * (q + 1) + (xcd - r) * q) + linb;
  const int m0 = (swz % gx) * BM;
  const int n0 = (swz / gx) * BN;

  const int St = K >> 5;
  const int Z = gridDim.z;
  const int zb = St / Z, zr = St - zb * Z;
  const int z = blockIdx.z;
  const int nst = zb + ((z < zr) ? 1 : 0);
  const int k0 = (z * zb + ((z < zr) ? z : zr)) << 5;

  const int wr = wave >> 2;    // 0..1 (row half)
  const int wc = wave & 3;     // 0..3 (col quarter, 64 cols each)
  const int lrow = lane >> 2;
  const int lcol = (lane & 3) << 3;
  const int fr = lane & 15;
  const int fq4 = (lane >> 4) << 2;
  const int kofs = (lane >> 4) << 3;
  const int kx = kofs ^ (((fr >> 1) & 3) << 3);

  f32x4 acc[8][4];
  #pragma unroll
  for (int m = 0; m < 8; ++m)
    #pragma unroll
    for (int n = 0; n < 4; ++n) acc[m][n] = (f32x4){0.f, 0.f, 0.f, 0.f};

  const u16* srcp[NJ];
  int loff[NJ];
  #pragma unroll
  for (int j = 0; j < NJ; ++j) {
    int g = j * 8 + wave;
    const u16* gb; int abase, trow, segi;
    if (g < 16)      { gb = Ah; abase = 0;         trow = m0; segi = g; }
    else if (g < 32) { gb = Al; abase = 8192;      trow = m0; segi = g - 16; }
    else if (g < 48) { gb = Bh; abase = 16384;     trow = n0; segi = g - 32; }
    else             { gb = Bl; abase = 24576;     trow = n0; segi = g - 48; }
    srcp[j] = gb + (size_t)(trow + segi * 16 + lrow) * K + (k0 + lcol);
    loff[j] = abase + segi * 512;
  }

  const int aoh0 = (wr * 128 + fr) * 32 + kx;           // + m*512
  const int aol0 = 8192 + aoh0;
  const int boh0 = 16384 + (wc * 64 + fr) * 32 + kx;    // + n*512
  const int bol0 = boh0 + 8192;

  #define ISSUE2(bufo, j0)                                             \
    { gload_lds16(srcp[j0], S + (bufo) + loff[j0]);  srcp[j0] += 32;   \
      gload_lds16(srcp[j0+1], S + (bufo) + loff[j0+1]); srcp[j0+1] += 32; }

  int curo = 0;
  ISSUE2(curo, 0); ISSUE2(curo, 2); ISSUE2(curo, 4); ISSUE2(curo, 6);

  for (int t = 0; t < nst; ++t) {
    const int nxt = curo ^ HALF;
    const bool more = (t + 1 < nst);   // block-uniform
    if (more) { ISSUE2(nxt, 0); WAITVM2(); } else { WAITVM0(); }
    BARRIER();                         // tile t landed for all waves

    short8 bh_[4], bl_[4];             // phase-invariant B fragments (regs)
    #pragma unroll
    for (int p = 0; p < 4; ++p) {
      const int m2 = 2 * p;
      short8 a0h = *(const short8*)(S + curo + aoh0 + m2 * 512);
      short8 a0l = *(const short8*)(S + curo + aol0 + m2 * 512);
      short8 a1h = *(const short8*)(S + curo + aoh0 + (m2 + 1) * 512);
      short8 a1l = *(const short8*)(S + curo + aol0 + (m2 + 1) * 512);
      if (p == 0) {
        #pragma unroll
        for (int n = 0; n < 4; ++n) {
          bh_[n] = *(const short8*)(S + curo + boh0 + n * 512);
          bl_[n] = *(const short8*)(S + curo + bol0 + n * 512);
        }
      }
      if (more) {
        if (p == 0) { ISSUE2(nxt, 2); }
        else if (p == 1) { ISSUE2(nxt, 4); }
        else if (p == 2) { ISSUE2(nxt, 6); }
      }
      BARRIER();
      __builtin_amdgcn_s_setprio(1);
      #pragma unroll
      for (int n = 0; n < 4; ++n) {
        acc[m2][n] = __builtin_amdgcn_mfma_f32_16x16x32_bf16(a0h, bh_[n], acc[m2][n], 0, 0, 0);
        acc[m2][n] = __builtin_amdgcn_mfma_f32_16x16x32_bf16(a0h, bl_[n], acc[m2][n], 0, 0, 0);
        acc[m2][n] = __builtin_amdgcn_mfma_f32_16x16x32_bf16(a0l, bh_[n], acc[m2][n], 0, 0, 0);
        acc[m2+1][n] = __builtin_amdgcn_mfma_f32_16x16x32_bf16(a1h, bh_[n], acc[m2+1][n], 0, 0, 0);
        acc[m2+1][n] = __builtin_amdgcn_mfma_f32_16x16x32_bf16(a1h, bl_[n], acc[m2+1][n], 0, 0, 0);
        acc[m2+1][n] = __builtin_amdgcn_mfma_f32_16x16x32_bf16(a1l, bh_[n], acc[m2+1][n], 0, 0, 0);
      }
      __builtin_amdgcn_s_setprio(0);
      BARRIER();
    }
    curo ^= HALF;
  }
  #undef ISSUE2

  if (CMODE == 2) {
    // fused h: n even = up chunk, n+1 = gate chunk, same logical 16 cols.
    float hm0 = 0.f, hm1 = 0.f;
    #pragma unroll
    for (int nn = 0; nn < 2; ++nn) {
      const int n = nn * 2;
      int lcol2 = (((n0 + wc * 64 + n * 16) >> 5) << 4) + fr;  // logical h col
      bool lo = lcol2 < 2752;
      #pragma unroll
      for (int m = 0; m < 8; ++m) {
        int row = m0 + wr * 128 + m * 16 + fq4;
        float* hp = C0 + (size_t)row * ldc + lcol2;
        f32x4 au = acc[m][n], ag = acc[m][n + 1];
        #pragma unroll
        for (int j = 0; j < 4; ++j) {
          float g = ag[j];
          float h = au[j] * (g / (1.f + expf(-g)));
          hp[(size_t)j * ldc] = h;
          float a = fabsf(h);
          if (lo) hm0 = fmaxf(hm0, a); else hm1 = fmaxf(hm1, a);
        }
      }
    }
    #pragma unroll
    for (int off = 32; off > 0; off >>= 1) {
      hm0 = fmaxf(hm0, __shfl_xor(hm0, off));
      hm1 = fmaxf(hm1, __shfl_xor(hm1, off));
    }
    if (lane == 0) {
      u32* slots = (u32*)C1;
      if (hm0 > 0.f) atomicMax(slots + SL_AH, __float_as_uint(hm0));
      if (hm1 > 0.f) atomicMax(slots + SL_AH + 1, __float_as_uint(hm1));
    }
  } else {
    float* Cz = (z < 4) ? (C0 + (size_t)z * M * ldc) : (C1 + (size_t)(z - 4) * M * ldc);
    #pragma unroll
    for (int m = 0; m < 8; ++m) {
      #pragma unroll
      for (int n = 0; n < 4; ++n) {
        int row = m0 + wr * 128 + m * 16 + fq4;
        int col = n0 + wc * 64 + n * 16 + fr;
        float* cp = Cz + (size_t)row * ldc + col;
        f32x4 a = acc[m][n];
        cp[0] = a[0];
        cp[(size_t)ldc] = a[1];
        cp[(size_t)2 * ldc] = a[2];
        cp[(size_t)3 * ldc] = a[3];
      }
    }
  }
}

// ---- out = sum of 8 partials (4 at p0, 4 at p1), fixed order ----
__global__ __launch_bounds__(256) void k_reduce8(const float4* __restrict__ p0,
                                                 const float4* __restrict__ p1,
                                                 float4* __restrict__ out, int nvec) {
  int stride = gridDim.x * blockDim.x;
  for (int i = blockIdx.x * blockDim.x + threadIdx.x; i < nvec; i += stride) {
    float4 s = p0[i];
    #pragma unroll
    for (int zz = 1; zz < 4; ++zz) {
      float4 b = p0[(size_t)zz * nvec + i];
      s.x += b.x; s.y += b.y; s.z += b.z; s.w += b.w;
    }
    #pragma unroll
    for (int zz = 0; zz < 4; ++zz) {
      float4 b = p1[(size_t)zz * nvec + i];
      s.x += b.x; s.y += b.y; s.z += b.z; s.w += b.w;
    }
    out[i] = s;
  }
}

// ---- out = p0+p1+p2+p3 (fallback reduce) ----
__global__ __launch_bounds__(256) void k_reduce4(const float4* __restrict__ p,
                                                 float4* __restrict__ out, int nvec) {
  int stride = gridDim.x * blockDim.x;
  for (int i = blockIdx.x * blockDim.x + threadIdx.x; i < nvec; i += stride) {
    float4 a = p[i], b = p[nvec + i], c = p[2 * nvec + i], d = p[3 * nvec + i];
    float4 o;
    o.x = ((a.x + b.x) + c.x) + d.x;
    o.y = ((a.y + b.y) + c.y) + d.y;
    o.z = ((a.z + b.z) + c.z) + d.z;
    o.w = ((a.w + b.w) + c.w) + d.w;
    out[i] = o;
  }
}

extern "C" void kernel_launch(void* const* d_in, const int* in_sizes, int n_in,
                              void* d_out, int out_size, void* d_ws, size_t ws_size,
                              hipStream_t stream) {
  const float* x  = (const float*)d_in[0];
  const float* ph = (const float*)d_in[1];
  const float* pi = (const float*)d_in[2];
  const float* pa = (const float*)d_in[3];
  const float* pw = (const float*)d_in[4];
  const float* Wg = (const float*)d_in[5];
  const float* Wu = (const float*)d_in[6];
  const float* Wd = (const float*)d_in[7];
  float* out = (float*)d_out;

  const u32 magic5504 = (u32)(((1ULL << 40) + 5503ULL) / 5504ULL);
  char* ws = (char*)d_ws;

  const size_t szX1 = (size_t)1024 * 3072 * 2;          // 6.29 MB each
  const size_t szWug = (size_t)11008 * 3072 * 2;        // 67.63 MB each (h, l)
  const size_t szH = (size_t)1024 * 5504 * 4;           // 22.54 MB
  const size_t szDP = (size_t)4 * 1024 * 2048 * 4;      // 33.55 MB (4 partials)
  const size_t fused_need = 1024 + 2 * szX1 + 2 * szWug + szH + szDP;  // ~204 MB

  if (ws_size >= fused_need) {
    // ---- fused path: interleaved upgate GEMM w/ h-epilogue + 8-phase down ----
    size_t off = 0;
    float* P = (float*)(ws + off); off += 1024;
    u16* X1h = (u16*)(ws + off); off += szX1;
    u16* X1l = (u16*)(ws + off); off += szX1;
    u16* Wh  = (u16*)(ws + off); off += szWug;   // interleaved up|gate rows
    u16* Wl  = (u16*)(ws + off); off += szWug;
    float* H = (float*)(ws + off); off += szH;
    float* DPz0 = (float*)(ws + off); off += szDP;
    // phase-2 aliases (upgate operands dead after fused GEMM):
    u16* X2h = Wh;
    u16* X2l = Wh + (size_t)1024 * 8256;
    float* DPz1 = (float*)(Wh + (size_t)2 * 1024 * 8256);  // 33.55 <= 33.81 MB tail
    u16* Wdh = Wl;
    u16* Wdl = Wl + (size_t)2048 * 8256;

    k_init<<<1, 64, 0, stream>>>(ph, pi, pa, pw, P);
    k_absmax4<<<1792, 256, 0, stream>>>(x, Wu, Wg, Wd, magic5504, P);
    k_params1<<<1, 64, 0, stream>>>(P);

    k_build1<<<1536 + 16512, 256, 0, stream>>>(x, Wu, Wg, P, X1h, X1l, Wh, Wl);

    // upgate: 8-phase 256x256, grid 4x43 = 172 blocks, z=1 (bit-exact full K);
    // h-fused epilogue writes H [1024][5504] + h-absmax into P
    dim3 g1(1024 / 256, 11008 / 256, 1);
    k_gemm8w<2><<<g1, 512, 0, stream>>>(X1h, X1l, Wh, Wl, H, P, 5504, 5504,
                                        1024, 11008, 3072);

    k_params2<<<1, 64, 0, stream>>>(P);

    k_build2<<<4128 + 8256, 256, 0, stream>>>(H, Wd, P, X2h, X2l, Wdh, Wdl);

    // down: 8-phase 256x256, split-K z=8 -> 256 blocks = exactly 1/CU
    dim3 g2(1024 / 256, 2048 / 256, 8);
    k_gemm8w<1><<<g2, 512, 0, stream>>>(X2h, X2l, Wdh, Wdl, DPz0, DPz1, 2048, 2048,
                                        1024, 2048, 8256);
    k_reduce8<<<2048, 256, 0, stream>>>((const float4*)DPz0, (const float4*)DPz1,
                                        (float4*)out, (1024 * 2048) / 4);
    return;
  }

  // ---------------- fallback: round-6 exact layout, proven kernels ----------------
  size_t off = 0;
  float* P = (float*)(ws + off); off += 1024;
  u16* X1h = (u16*)(ws + off); off += szX1;
  u16* X1l = (u16*)(ws + off); off += szX1;
  u16* Wh  = (u16*)(ws + off); off += (size_t)5504 * 3072 * 2;
  u16* Wl  = (u16*)(ws + off); off += (size_t)5504 * 3072 * 2;
  float* UP   = (float*)(ws + off); off += (size_t)1024 * 5504 * 4;
  float* GATE = (float*)(ws + off); off += (size_t)1024 * 5504 * 4;
  u16* X2h = (u16*)(ws + off); off += (size_t)1024 * 8256 * 2;
  u16* X2l = (u16*)(ws + off); off += (size_t)1024 * 8256 * 2;
  float* H = UP;
  float* DPART = UP;
  if (ws_size < off) return;

  k_init<<<1, 64, 0, stream>>>(ph, pi, pa, pw, P);
  k_absmax4<<<1792, 256, 0, stream>>>(x, Wu, Wg, Wd, magic5504, P);
  k_params1<<<1, 64, 0, stream>>>(P);

  {
    int nch = 1024 * (3072 / 8);
    k_build_x<<<(nch + 255) / 256, 256, 0, stream>>>(x, P, X1h, X1l, 1024, 2048, 1024, 3072, P_SX);
  }
  {
    int nch = 5504 * (3072 / 8);
    k_build_w<<<(nch + 255) / 256, 256, 0, stream>>>(Wu, P, Wh, Wl, 5504, 2048, 1024, 3072, P_SWUP, 2752);
  }
  dim3 g1(1024 / 128, 5504 / 128, 1);
  k_gemm<4, 4><<<g1, 256, 0, stream>>>(X1h, X1l, Wh, Wl, UP, UP, 5504, 5504, 1024, 5504, 3072);
  {
    int nch = 5504 * (3072 / 8);
    k_build_w<<<(nch + 255) / 256, 256, 0, stream>>>(Wg, P, Wh, Wl, 5504, 2048, 1024, 3072, P_SWGATE, 2752);
  }
  k_gemm<4, 4><<<g1, 256, 0, stream>>>(X1h, X1l, Wh, Wl, GATE, GATE, 5504, 5504, 1024, 5504, 3072);

  k_h<<<2048, 256, 0, stream>>>(UP, GATE, H, P);
  k_params2<<<1, 64, 0, stream>>>(P);

  {
    int nch = 1024 * (8256 / 8);
    k_build_x<<<(nch + 255) / 256, 256, 0, stream>>>(H, P, X2h, X2l, 1024, 5504, 2752, 8256, P_SH);
  }
  {
    int nch = 2048 * (8256 / 8);
    k_build_w<<<(nch + 255) / 256, 256, 0, stream>>>(Wd, P, Wh, Wl, 2048, 5504, 2752, 8256, P_SWDOWN, 1024);
  }
  dim3 g2(1024 / 128, 2048 / 128, 4);
  k_gemm<4, 4><<<g2, 256, 0, stream>>>(X2h, X2l, Wh, Wl, DPART, DPART, 2048, 2048, 1024, 2048, 8256);
  k_reduce4<<<2048, 256, 0, stream>>>((const float4*)DPART, (float4*)out, (1024 * 2048) / 4);
}